// Round 12
// baseline (249.541 us; speedup 1.0000x reference)
//
#include <hip/hip_runtime.h>
#include <hip/hip_bf16.h>

typedef __bf16 bf16_t;
typedef __bf16 bf16x8 __attribute__((ext_vector_type(8)));
typedef float f32x4 __attribute__((ext_vector_type(4)));
typedef float f32x16 __attribute__((ext_vector_type(16)));
typedef unsigned short u16;

#define DEVI __device__ __forceinline__
#define MFMA16x16x32(A, B, C) __builtin_amdgcn_mfma_f32_16x16x32_bf16(A, B, C, 0, 0, 0)
#define MFMA32x32x16(A, B, C) __builtin_amdgcn_mfma_f32_32x32x16_bf16(A, B, C, 0, 0, 0)

DEVI void gload_lds16(const void* g, void* l) {
  __builtin_amdgcn_global_load_lds(
      (const __attribute__((address_space(1))) void*)g,
      (__attribute__((address_space(3))) void*)l, 16, 0, 0);
}

DEVI u16 bits_of(bf16_t x) { return __builtin_bit_cast(u16, x); }

DEVI unsigned pk2(float lo, float hi) {
  return (unsigned)bits_of((bf16_t)lo) | ((unsigned)bits_of((bf16_t)hi) << 16);
}

DEVI bf16x8 mk_frag(unsigned s0, unsigned s1, unsigned s2, unsigned s3) {
  int4 t;
  t.x = (int)s0; t.y = (int)s1; t.z = (int)s2; t.w = (int)s3;
  return __builtin_bit_cast(bf16x8, t);
}

#if __has_builtin(__builtin_amdgcn_exp2f)
DEVI float exp2_fast(float x) { return __builtin_amdgcn_exp2f(x); }
#else
DEVI float exp2_fast(float x) { return __exp2f(x); }
#endif

// ---------------- fused fp32 -> bf16 conversion: X + 4 weight matrices ----------------
__global__ void cvt_all(const float4* __restrict__ X,
                        const float4* __restrict__ Wq, const float4* __restrict__ Wk,
                        const float4* __restrict__ Wv, const float4* __restrict__ Wo,
                        ushort4* __restrict__ out) {
  int i = blockIdx.x * 256 + threadIdx.x;   // 0 .. 2097151 float4s
  const float4* src;
  int off;
  if (i < 1048576) { src = X; off = i; }
  else {
    int j = i - 1048576;
    int seg = j >> 18;
    off = j & 262143;
    src = (seg == 0) ? Wq : (seg == 1) ? Wk : (seg == 2) ? Wv : Wo;
  }
  float4 v = src[off];
  ushort4 o;
  o.x = bits_of((bf16_t)v.x);
  o.y = bits_of((bf16_t)v.y);
  o.z = bits_of((bf16_t)v.z);
  o.w = bits_of((bf16_t)v.w);
  out[i] = o;
}

// ---------------- QKV GEMM: 128x128 tile, bf16 out (proven ~760 TF) ----------------
__global__ __launch_bounds__(256, 3) void gemm_bt(
    const bf16_t* __restrict__ A,
    const bf16_t* __restrict__ W0, const bf16_t* __restrict__ W1, const bf16_t* __restrict__ W2,
    const float* __restrict__ b0, const float* __restrict__ b1, const float* __restrict__ b2,
    bf16_t* o0, bf16_t* o1, bf16_t* o2, float s0, float s1, float s2) {
  constexpr int K = 1024, N = 1024;
  const int z = blockIdx.z;
  const bf16_t* W = (z == 0) ? W0 : ((z == 1) ? W1 : W2);
  const float* bias = (z == 0) ? b0 : ((z == 1) ? b1 : b2);
  bf16_t* out = (z == 0) ? o0 : ((z == 1) ? o1 : o2);
  const float scale = (z == 0) ? s0 : ((z == 1) ? s1 : s2);

  __shared__ bf16_t As[128 * 32];
  __shared__ bf16_t Bs[128 * 32];

  const int tid = threadIdx.x;
  const int wave = tid >> 6, lane = tid & 63;
  const int g = lane >> 4, l15 = lane & 15;
  const long m0 = (long)blockIdx.x * 128;
  const long n0 = (long)blockIdx.y * 128;

  const int srow = lane >> 2;
  const int scol = (lane & 3) * 8;

  const int wr = (wave >> 1) * 64;
  const int wc = (wave & 1) * 64;

  f32x4 acc[4][4] = {};

  for (int k0 = 0; k0 < K; k0 += 32) {
    __syncthreads();
#pragma unroll
    for (int t = 0; t < 2; ++t) {
      int chunk = wave * 2 + t;
      int row = chunk * 16 + srow;
      gload_lds16(A + (m0 + row) * K + k0 + scol, (char*)As + chunk * 1024);
      gload_lds16(W + (n0 + row) * K + k0 + scol, (char*)Bs + chunk * 1024);
    }
    __syncthreads();

    bf16x8 af[4], bfr[4];
#pragma unroll
    for (int i = 0; i < 4; ++i)
      af[i] = *(const bf16x8*)(As + (wr + i * 16 + l15) * 32 + g * 8);
#pragma unroll
    for (int i = 0; i < 4; ++i)
      bfr[i] = *(const bf16x8*)(Bs + (wc + i * 16 + l15) * 32 + g * 8);
    __builtin_amdgcn_s_setprio(1);
#pragma unroll
    for (int mi = 0; mi < 4; ++mi)
#pragma unroll
      for (int ni = 0; ni < 4; ++ni)
        acc[mi][ni] = MFMA16x16x32(af[mi], bfr[ni], acc[mi][ni]);
    __builtin_amdgcn_s_setprio(0);
  }

#pragma unroll
  for (int ni = 0; ni < 4; ++ni) {
    long col = n0 + wc + ni * 16 + l15;
    float bv = bias[col];
#pragma unroll
    for (int mi = 0; mi < 4; ++mi) {
#pragma unroll
      for (int r = 0; r < 4; ++r) {
        long row = m0 + wr + mi * 16 + g * 4 + r;
        out[row * N + col] = (bf16_t)((acc[mi][ni][r] + bv) * scale);
      }
    }
  }
}

// ---------------- O-projection GEMM: 128x64 tile, f32 out (R11, 512 blocks = 2/CU) --------
__global__ __launch_bounds__(256, 3) void gemm_o64(
    const bf16_t* __restrict__ A, const bf16_t* __restrict__ W,
    const float* __restrict__ bias, float* __restrict__ out) {
  constexpr int K = 1024, N = 1024;
  __shared__ bf16_t As[128 * 32];
  __shared__ bf16_t Bs[64 * 32];

  const int tid = threadIdx.x;
  const int wave = tid >> 6, lane = tid & 63;
  const int g = lane >> 4, l15 = lane & 15;
  const long m0 = (long)blockIdx.x * 128;
  const long n0 = (long)blockIdx.y * 64;

  const int srow = lane >> 2;
  const int scol = (lane & 3) * 8;

  const int wr = (wave >> 1) * 64;
  const int wc = (wave & 1) * 32;

  f32x4 acc[4][2] = {};

  for (int k0 = 0; k0 < K; k0 += 32) {
    __syncthreads();
#pragma unroll
    for (int c = 0; c < 3; ++c) {
      int idx = wave * 3 + c;
      if (idx < 8) {
        int row = idx * 16 + srow;
        gload_lds16(A + (m0 + row) * K + k0 + scol, (char*)As + idx * 1024);
      } else {
        int row = (idx - 8) * 16 + srow;
        gload_lds16(W + (n0 + row) * K + k0 + scol, (char*)Bs + (idx - 8) * 1024);
      }
    }
    __syncthreads();

    bf16x8 af[4], bfr[2];
#pragma unroll
    for (int i = 0; i < 4; ++i)
      af[i] = *(const bf16x8*)(As + (wr + i * 16 + l15) * 32 + g * 8);
#pragma unroll
    for (int i = 0; i < 2; ++i)
      bfr[i] = *(const bf16x8*)(Bs + (wc + i * 16 + l15) * 32 + g * 8);
    __builtin_amdgcn_s_setprio(1);
#pragma unroll
    for (int mi = 0; mi < 4; ++mi)
#pragma unroll
      for (int ni = 0; ni < 2; ++ni)
        acc[mi][ni] = MFMA16x16x32(af[mi], bfr[ni], acc[mi][ni]);
    __builtin_amdgcn_s_setprio(0);
  }

#pragma unroll
  for (int ni = 0; ni < 2; ++ni) {
    long col = n0 + wc + ni * 16 + l15;
    float bv = bias[col];
#pragma unroll
    for (int mi = 0; mi < 4; ++mi) {
#pragma unroll
      for (int r = 0; r < 4; ++r) {
        long row = m0 + wr + mi * 16 + g * 4 + r;
        out[row * N + col] = acc[mi][ni][r] + bv;
      }
    }
  }
}

// ---------------- Flash attention: intra-block KV-split, 4 waves, in-block merge ----------
// grid (32 qb x 32 bh) = 1024 blocks x 256 threads = 4096 waves (4/SIMD at 4 blocks/CU).
// Waves 0,1 (pair A) = keys 0..1023; waves 2,3 (pair B) = keys 1024..2047; both cover the
// same 64 q-rows (waveq = wave&1 -> 32 q each). Pair-private single-buffered K/V LDS (16K
// per pair) + shared mask 8K = 40960 B -> 4 blocks/CU; __launch_bounds__(256,4) -> VGPR
// budget 128 (kernel ~110, no spill -- R9 lesson). Loop = R10's proven 2-barrier phased
// skeleton, pairs in lockstep. Deferred-PV (T15). Merge in-block via LDS (R4 algebra).
__global__ __launch_bounds__(256, 4) void attn_fwd9(
    const bf16_t* __restrict__ Qm, const bf16_t* __restrict__ Km,
    const bf16_t* __restrict__ Vm, const float* __restrict__ mask,
    bf16_t* __restrict__ ctx) {
  constexpr int S = 2048, Hs = 1024;
  constexpr float L2E = 1.4426950408889634f;
  // bijective XCD swizzle: 1024 blocks -> 128 consecutive per XCD
  int id = blockIdx.y * 32 + blockIdx.x;
  int swz = ((id & 7) << 7) | (id >> 3);
  const int qb = swz & 31;
  const int bh = swz >> 5;
  const int b = bh >> 4, h = bh & 15;

  const int tid = threadIdx.x;          // 0..255
  const int wave = tid >> 6, lane = tid & 63;
  const int pair = wave >> 1;           // 0: keys 0..1023, 1: keys 1024..2047
  const int waveq = wave & 1;           // q sub-block (32 rows each)
  const int l31 = lane & 31, hi = lane >> 5;
  const int koff = pair * 1024;

  __shared__ bf16_t Kb_[2][64 * 64];   // per-pair K [key][d], swizzled; 16 KB
  __shared__ bf16_t Vb_[2][64 * 64];   // per-pair V [d][key], swizzled; 16 KB
  __shared__ float Ms[2048];           // full mask row (f32); 8 KB

  const char* Kg = (const char*)(Km + ((long)b * S + koff) * Hs + h * 64);
  const bf16_t* Vg = Vm + ((long)b * S + koff) * Hs + h * 64;
  const float* mrow = mask + b * S;

  // hoisted Q B-fragments: col=q=l31, k-slot d = ks*16 + hi*8 + j
  const long qrow = (long)b * S + qb * 64 + waveq * 32 + l31;
  const bf16_t* Qr = Qm + qrow * Hs + h * 64 + hi * 8;
  bf16x8 qB[4];
#pragma unroll
  for (int ks = 0; ks < 4; ++ks) qB[ks] = *(const bf16x8*)(Qr + ks * 16);

  // V staging: pair-local thread covers keys 4ka..4ka+3 x d dq*8..dq*8+7
  const int ptid = tid & 127;
  const int ka = ptid & 15, dq = ptid >> 4;
  const bf16_t* Vsrc0 = Vg + (long)(4 * ka) * Hs + dq * 8;

  // K staging: per pair 8 chunks of 1024B (8 rows each), 4 per wave; pre-swizzled source
  const int krow_in8 = lane >> 3;
  const int kslot = (lane & 7) ^ krow_in8;

  // ---- prologue: mask (8 chunks over 4 waves) + stage tile 0 ----
#pragma unroll
  for (int c = 0; c < 2; ++c) {
    int ch = wave * 2 + c;               // 0..7
    gload_lds16((const char*)mrow + ch * 1024 + lane * 16, (char*)Ms + ch * 1024);
  }
  int4 v0 = *(const int4*)(Vsrc0);
  int4 v1 = *(const int4*)(Vsrc0 + Hs);
  int4 v2 = *(const int4*)(Vsrc0 + 2 * Hs);
  int4 v3 = *(const int4*)(Vsrc0 + 3 * Hs);
  {
    const u16* p0 = (const u16*)&v0; const u16* p1 = (const u16*)&v1;
    const u16* p2 = (const u16*)&v2; const u16* p3 = (const u16*)&v3;
#pragma unroll
    for (int j = 0; j < 8; ++j) {
      int d = dq * 8 + j;
      int2 w;
      w.x = (int)((unsigned)p0[j] | ((unsigned)p1[j] << 16));
      w.y = (int)((unsigned)p2[j] | ((unsigned)p3[j] << 16));
      *(int2*)((char*)Vb_[pair] + d * 128 + ((8 * ka) ^ (j << 4))) = w;
    }
  }
#pragma unroll
  for (int c = 0; c < 4; ++c) {
    int ch = waveq * 4 + c;              // chunk 0..7 within pair's K buffer
    gload_lds16(Kg + (long)(ch * 8 + krow_in8) * (Hs * 2) + kslot * 16,
                (char*)Kb_[pair] + ch * 1024);
  }
  __syncthreads();

  f32x16 acc0 = {}, acc1 = {};
  float rho = 0.0f, lrun = 0.0f;
  bf16x8 pbP[4] = {};   // packed P(t-1)
  bf16x8 vaP[8] = {};   // V^T frags of tile t-1

  for (int t = 0; t < 16; ++t) {
    const char* kb_c = (const char*)Kb_[pair];
    const char* vb_c = (const char*)Vb_[pair];

    // issue V(t+1) reg loads early: drained at compute-end barrier under compute cover (T14)
    if (t < 15) {
      const bf16_t* Vs = Vsrc0 + (long)((t + 1) * 64) * Hs;
      v0 = *(const int4*)(Vs);
      v1 = *(const int4*)(Vs + Hs);
      v2 = *(const int4*)(Vs + 2 * Hs);
      v3 = *(const int4*)(Vs + 3 * Hs);
    }

    // K-fragments for QK (LDS)
    bf16x8 kf0[4], kf1[4];
#pragma unroll
    for (int ks = 0; ks < 4; ++ks)
      kf0[ks] = *(const bf16x8*)(kb_c + l31 * 128 + (((2 * ks + hi) * 16) ^ ((l31 & 7) << 4)));
#pragma unroll
    for (int ks = 0; ks < 4; ++ks) {
      int row = 32 + l31;
      kf1[ks] = *(const bf16x8*)(kb_c + row * 128 + (((2 * ks + hi) * 16) ^ ((row & 7) << 4)));
    }

    // mask from LDS (lgkm; pair offset)
    const float* mbase = Ms + pair * 1024 + t * 64;
    float4 mk[8];
#pragma unroll
    for (int st = 0; st < 2; ++st)
#pragma unroll
      for (int rg = 0; rg < 4; ++rg)
        mk[st * 4 + rg] = *(const float4*)(mbase + st * 32 + rg * 8 + hi * 4);

    // ---- QK^T: D[key][q] (log2-domain) ----
    f32x16 sc0 = {}, sc1 = {};
    __builtin_amdgcn_s_setprio(1);
#pragma unroll
    for (int ks = 0; ks < 4; ++ks) sc0 = MFMA32x32x16(kf0[ks], qB[ks], sc0);
#pragma unroll
    for (int ks = 0; ks < 4; ++ks) sc1 = MFMA32x32x16(kf1[ks], qB[ks], sc1);
    __builtin_amdgcn_s_setprio(0);

    // ---- PV(t-1): register-only, overlaps softmax below ----
    if (t > 0) {
      __builtin_amdgcn_s_setprio(1);
#pragma unroll
      for (int i5 = 0; i5 < 4; ++i5) {
        acc0 = MFMA32x32x16(vaP[i5 * 2 + 0], pbP[i5], acc0);
        acc1 = MFMA32x32x16(vaP[i5 * 2 + 1], pbP[i5], acc1);
      }
      __builtin_amdgcn_s_setprio(0);
    }

    // ---- read V^T frags of tile t (consumed next iteration; register-carried) ----
#pragma unroll
    for (int st = 0; st < 2; ++st)
#pragma unroll
      for (int ks2 = 0; ks2 < 2; ++ks2) {
        int slot = st * 4 + ks2 * 2 + hi;
        int i5 = st * 2 + ks2;
        vaP[i5 * 2 + 0] = *(const bf16x8*)(vb_c + l31 * 128 + ((slot * 16) ^ ((l31 & 7) << 4)));
        int d1 = 32 + l31;
        vaP[i5 * 2 + 1] = *(const bf16x8*)(vb_c + d1 * 128 + ((slot * 16) ^ ((d1 & 7) << 4)));
      }

    // ---- t = r + mask*log2e; row max via 4 chains ----
    float m4[4] = {-1e30f, -1e30f, -1e30f, -1e30f};
#pragma unroll
    for (int st = 0; st < 2; ++st) {
      f32x16& s = st ? sc1 : sc0;
#pragma unroll
      for (int rg = 0; rg < 4; ++rg) {
        float4 m = mk[st * 4 + rg];
#pragma unroll
        for (int i = 0; i < 4; ++i) {
          float v = fmaf(((const float*)&m)[i], L2E, s[rg * 4 + i]);
          s[rg * 4 + i] = v;
          m4[i] = fmaxf(m4[i], v);
        }
      }
    }
    float mt = fmaxf(fmaxf(m4[0], m4[1]), fmaxf(m4[2], m4[3]));
    mt = fmaxf(mt, __shfl_xor(mt, 32, 64));

    // ---- rare rescale: keep exp2 arg <= 24 ----
    if (!__all(mt - rho <= 24.0f)) {
      float mw = mt;
#pragma unroll
      for (int off = 1; off < 32; off <<= 1) mw = fmaxf(mw, __shfl_xor(mw, off, 64));
      float fct = exp2_fast(rho - mw);   // uniform
      lrun *= fct;
#pragma unroll
      for (int i = 0; i < 16; ++i) { acc0[i] *= fct; acc1[i] *= fct; }
      rho = mw;
    }
    float rho_u = __builtin_amdgcn_readfirstlane(rho);
    if (rho_u != 0.0f) {
#pragma unroll
      for (int i = 0; i < 16; ++i) { sc0[i] -= rho_u; sc1[i] -= rho_u; }
    }

    // ---- p = exp2(t); sum via 4 chains ----
    float s4[4] = {0.f, 0.f, 0.f, 0.f};
#pragma unroll
    for (int st = 0; st < 2; ++st) {
      f32x16& s = st ? sc1 : sc0;
#pragma unroll
      for (int i = 0; i < 16; ++i) {
        float p = exp2_fast(s[i]);
        s[i] = p;
        s4[i & 3] += p;
      }
    }
    float ls = (s4[0] + s4[1]) + (s4[2] + s4[3]);
    ls += __shfl_xor(ls, 32, 64);
    lrun += ls;

    // ---- pack P(t) -> pbP (consumed next iteration) ----
#pragma unroll
    for (int st = 0; st < 2; ++st) {
      f32x16& s = st ? sc1 : sc0;
      unsigned a0 = pk2(s[0], s[1]),   c0 = pk2(s[4], s[5]);
      unsigned a1 = pk2(s[2], s[3]),   c1 = pk2(s[6], s[7]);
      unsigned a2 = pk2(s[8], s[9]),   c2 = pk2(s[12], s[13]);
      unsigned a3 = pk2(s[10], s[11]), c3 = pk2(s[14], s[15]);
      asm("v_permlane32_swap_b32 %0, %1" : "+v"(a0), "+v"(c0));
      asm("v_permlane32_swap_b32 %0, %1" : "+v"(a1), "+v"(c1));
      asm("v_permlane32_swap_b32 %0, %1" : "+v"(a2), "+v"(c2));
      asm("v_permlane32_swap_b32 %0, %1" : "+v"(a3), "+v"(c3));
      pbP[st * 2 + 0] = mk_frag(a0, a1, c0, c1);   // keys st*32 + 0..15
      pbP[st * 2 + 1] = mk_frag(a2, a3, c2, c3);   // keys st*32 + 16..31
    }
    __syncthreads();   // compute done: all LDS reads of tile t retired; V(t+1) loads drained

    // ---- stage phase: write V(t+1), issue K(t+1) into pair buffer ----
    if (t < 15) {
      const u16* p0 = (const u16*)&v0; const u16* p1 = (const u16*)&v1;
      const u16* p2 = (const u16*)&v2; const u16* p3 = (const u16*)&v3;
#pragma unroll
      for (int j = 0; j < 8; ++j) {
        int d = dq * 8 + j;
        int2 w;
        w.x = (int)((unsigned)p0[j] | ((unsigned)p1[j] << 16));
        w.y = (int)((unsigned)p2[j] | ((unsigned)p3[j] << 16));
        *(int2*)((char*)Vb_[pair] + d * 128 + ((8 * ka) ^ (j << 4))) = w;
      }
#pragma unroll
      for (int c = 0; c < 4; ++c) {
        int ch = waveq * 4 + c;
        gload_lds16(Kg + (long)((t + 1) * 64 + ch * 8 + krow_in8) * (Hs * 2) + kslot * 16,
                    (char*)Kb_[pair] + ch * 1024);
      }
      __syncthreads();   // staged data visible
    }
  }

  // ---- flush PV(15) ----
  __builtin_amdgcn_s_setprio(1);
#pragma unroll
  for (int i5 = 0; i5 < 4; ++i5) {
    acc0 = MFMA32x32x16(vaP[i5 * 2 + 0], pbP[i5], acc0);
    acc1 = MFMA32x32x16(vaP[i5 * 2 + 1], pbP[i5], acc1);
  }
  __builtin_amdgcn_s_setprio(0);

  // ---- in-block merge: pair B publishes partials via LDS (reuse Kb_ + Ms regions) ----
  float* accL = (float*)Kb_;        // 16 KB: [waveq][lane][32 f32]
  float2* lrL = (float2*)Ms;        // 64 entries: [waveq*32 + l31]
  if (pair == 1) {
    float* dst = accL + waveq * 2048 + lane * 32;
#pragma unroll
    for (int i = 0; i < 16; ++i) dst[i] = acc0[i];
#pragma unroll
    for (int i = 0; i < 16; ++i) dst[16 + i] = acc1[i];
    if (hi == 0) lrL[waveq * 32 + l31] = make_float2(lrun, rho);
  }
  __syncthreads();
  if (pair == 0) {
    const float* src = accL + waveq * 2048 + lane * 32;
    float2 lrB = lrL[waveq * 32 + l31];
    float M = fmaxf(rho, lrB.y);
    float wA = exp2_fast(rho - M), wB = exp2_fast(lrB.y - M);
    float inv = 1.0f / (lrun * wA + lrB.x * wB);
    wA *= inv; wB *= inv;
    bf16_t* cb = ctx + qrow * Hs + h * 64;
#pragma unroll
    for (int dh = 0; dh < 2; ++dh) {
      f32x16& a = dh ? acc1 : acc0;
      const float* sb = src + dh * 16;
#pragma unroll
      for (int rg = 0; rg < 4; ++rg) {
        ushort4 o;
        o.x = bits_of((bf16_t)(a[rg * 4 + 0] * wA + sb[rg * 4 + 0] * wB));
        o.y = bits_of((bf16_t)(a[rg * 4 + 1] * wA + sb[rg * 4 + 1] * wB));
        o.z = bits_of((bf16_t)(a[rg * 4 + 2] * wA + sb[rg * 4 + 2] * wB));
        o.w = bits_of((bf16_t)(a[rg * 4 + 3] * wA + sb[rg * 4 + 3] * wB));
        *(ushort4*)(cb + dh * 32 + rg * 8 + hi * 4) = o;
      }
    }
  }
}

// ---------------- launcher ----------------
extern "C" void kernel_launch(void* const* d_in, const int* in_sizes, int n_in,
                              void* d_out, int out_size, void* d_ws, size_t ws_size,
                              hipStream_t stream) {
  (void)in_sizes; (void)n_in; (void)out_size; (void)ws_size;
  const float* X  = (const float*)d_in[0];
  const float* mask = (const float*)d_in[1];
  const float* Wq = (const float*)d_in[2];
  const float* bq = (const float*)d_in[3];
  const float* Wk = (const float*)d_in[4];
  const float* bk = (const float*)d_in[5];
  const float* Wv = (const float*)d_in[6];
  const float* bv = (const float*)d_in[7];
  const float* Wo = (const float*)d_in[8];
  const float* bo = (const float*)d_in[9];

  char* ws = (char*)d_ws;
  bf16_t* Xb  = (bf16_t*)(ws + 0);          // dead after QKV GEMM
  bf16_t* Wqb = (bf16_t*)(ws + 8388608);
  bf16_t* Wkb = (bf16_t*)(ws + 10485760);
  bf16_t* Wvb = (bf16_t*)(ws + 12582912);
  bf16_t* Wob = (bf16_t*)(ws + 14680064);   // LIVE until O-GEMM
  bf16_t* Qb  = (bf16_t*)(ws + 16777216);
  bf16_t* Kb  = (bf16_t*)(ws + 25165824);
  bf16_t* Vb  = (bf16_t*)(ws + 33554432);
  bf16_t* Cb  = (bf16_t*)(ws + 41943040);   // ctx bf16 (dedicated)

  cvt_all<<<8192, 256, 0, stream>>>((const float4*)X, (const float4*)Wq, (const float4*)Wk,
                                    (const float4*)Wv, (const float4*)Wo, (ushort4*)Xb);

  // QKV projections; Q pre-scaled by 0.125*log2e so attention scores are log2-domain
  const float QSCALE = 0.125f * 1.4426950408889634f;
  dim3 gq(32, 8, 3);
  gemm_bt<<<gq, 256, 0, stream>>>(Xb, Wqb, Wkb, Wvb, bq, bk, bv, Qb, Kb, Vb,
                                  QSCALE, 1.0f, 1.0f);

  // attention (intra-block KV-split, in-block merge)
  dim3 ga(32, 32, 1);
  attn_fwd9<<<ga, 256, 0, stream>>>(Qb, Kb, Vb, mask, Cb);

  // output projection -> f32 d_out (128x64 tiles, 512 blocks = 2/CU)
  dim3 go(32, 16, 1);
  gemm_o64<<<go, 256, 0, stream>>>(Cb, Wob, bo, (float*)d_out);
}

// Round 13
// 128.109 us; speedup vs baseline: 1.9479x; 1.9479x over previous
//
#include <hip/hip_runtime.h>
#include <hip/hip_bf16.h>

typedef __bf16 bf16_t;
typedef __bf16 bf16x8 __attribute__((ext_vector_type(8)));
typedef float f32x4 __attribute__((ext_vector_type(4)));
typedef float f32x16 __attribute__((ext_vector_type(16)));
typedef unsigned short u16;

#define DEVI __device__ __forceinline__
#define MFMA16x16x32(A, B, C) __builtin_amdgcn_mfma_f32_16x16x32_bf16(A, B, C, 0, 0, 0)
#define MFMA32x32x16(A, B, C) __builtin_amdgcn_mfma_f32_32x32x16_bf16(A, B, C, 0, 0, 0)

DEVI void gload_lds16(const void* g, void* l) {
  __builtin_amdgcn_global_load_lds(
      (const __attribute__((address_space(1))) void*)g,
      (__attribute__((address_space(3))) void*)l, 16, 0, 0);
}

DEVI u16 bits_of(bf16_t x) { return __builtin_bit_cast(u16, x); }

DEVI unsigned pk2(float lo, float hi) {
  return (unsigned)bits_of((bf16_t)lo) | ((unsigned)bits_of((bf16_t)hi) << 16);
}

DEVI bf16x8 mk_frag(unsigned s0, unsigned s1, unsigned s2, unsigned s3) {
  int4 t;
  t.x = (int)s0; t.y = (int)s1; t.z = (int)s2; t.w = (int)s3;
  return __builtin_bit_cast(bf16x8, t);
}

#if __has_builtin(__builtin_amdgcn_exp2f)
DEVI float exp2_fast(float x) { return __builtin_amdgcn_exp2f(x); }
#else
DEVI float exp2_fast(float x) { return __exp2f(x); }
#endif

// ---------------- fused fp32 -> bf16 conversion: X + 4 weight matrices ----------------
__global__ void cvt_all(const float4* __restrict__ X,
                        const float4* __restrict__ Wq, const float4* __restrict__ Wk,
                        const float4* __restrict__ Wv, const float4* __restrict__ Wo,
                        ushort4* __restrict__ out) {
  int i = blockIdx.x * 256 + threadIdx.x;   // 0 .. 2097151 float4s
  const float4* src;
  int off;
  if (i < 1048576) { src = X; off = i; }
  else {
    int j = i - 1048576;
    int seg = j >> 18;
    off = j & 262143;
    src = (seg == 0) ? Wq : (seg == 1) ? Wk : (seg == 2) ? Wv : Wo;
  }
  float4 v = src[off];
  ushort4 o;
  o.x = bits_of((bf16_t)v.x);
  o.y = bits_of((bf16_t)v.y);
  o.z = bits_of((bf16_t)v.z);
  o.w = bits_of((bf16_t)v.w);
  out[i] = o;
}

// ---------------- QKV GEMM: out[m][n] = (sum_k A[m][k]*W[n][k] + bias[n]) * scale ----------------
// 128x128 tile, bf16 out. Proven ~760 TF at 3 blocks/CU.
__global__ __launch_bounds__(256, 3) void gemm_bt(
    const bf16_t* __restrict__ A,
    const bf16_t* __restrict__ W0, const bf16_t* __restrict__ W1, const bf16_t* __restrict__ W2,
    const float* __restrict__ b0, const float* __restrict__ b1, const float* __restrict__ b2,
    bf16_t* o0, bf16_t* o1, bf16_t* o2, float s0, float s1, float s2) {
  constexpr int K = 1024, N = 1024;
  const int z = blockIdx.z;
  const bf16_t* W = (z == 0) ? W0 : ((z == 1) ? W1 : W2);
  const float* bias = (z == 0) ? b0 : ((z == 1) ? b1 : b2);
  bf16_t* out = (z == 0) ? o0 : ((z == 1) ? o1 : o2);
  const float scale = (z == 0) ? s0 : ((z == 1) ? s1 : s2);

  __shared__ bf16_t As[128 * 32];
  __shared__ bf16_t Bs[128 * 32];

  const int tid = threadIdx.x;
  const int wave = tid >> 6, lane = tid & 63;
  const int g = lane >> 4, l15 = lane & 15;
  const long m0 = (long)blockIdx.x * 128;
  const long n0 = (long)blockIdx.y * 128;

  const int srow = lane >> 2;
  const int scol = (lane & 3) * 8;

  const int wr = (wave >> 1) * 64;
  const int wc = (wave & 1) * 64;

  f32x4 acc[4][4] = {};

  for (int k0 = 0; k0 < K; k0 += 32) {
    __syncthreads();
#pragma unroll
    for (int t = 0; t < 2; ++t) {
      int chunk = wave * 2 + t;
      int row = chunk * 16 + srow;
      gload_lds16(A + (m0 + row) * K + k0 + scol, (char*)As + chunk * 1024);
      gload_lds16(W + (n0 + row) * K + k0 + scol, (char*)Bs + chunk * 1024);
    }
    __syncthreads();

    bf16x8 af[4], bfr[4];
#pragma unroll
    for (int i = 0; i < 4; ++i)
      af[i] = *(const bf16x8*)(As + (wr + i * 16 + l15) * 32 + g * 8);
#pragma unroll
    for (int i = 0; i < 4; ++i)
      bfr[i] = *(const bf16x8*)(Bs + (wc + i * 16 + l15) * 32 + g * 8);
    __builtin_amdgcn_s_setprio(1);
#pragma unroll
    for (int mi = 0; mi < 4; ++mi)
#pragma unroll
      for (int ni = 0; ni < 4; ++ni)
        acc[mi][ni] = MFMA16x16x32(af[mi], bfr[ni], acc[mi][ni]);
    __builtin_amdgcn_s_setprio(0);
  }

#pragma unroll
  for (int ni = 0; ni < 4; ++ni) {
    long col = n0 + wc + ni * 16 + l15;
    float bv = bias[col];
#pragma unroll
    for (int mi = 0; mi < 4; ++mi) {
#pragma unroll
      for (int r = 0; r < 4; ++r) {
        long row = m0 + wr + mi * 16 + g * 4 + r;
        out[row * N + col] = (bf16_t)((acc[mi][ni][r] + bv) * scale);
      }
    }
  }
}

// ---------------- O-projection GEMM: 128x64 tile, f32 out (512 blocks = 2/CU) ----------------
__global__ __launch_bounds__(256, 3) void gemm_o64(
    const bf16_t* __restrict__ A, const bf16_t* __restrict__ W,
    const float* __restrict__ bias, float* __restrict__ out) {
  constexpr int K = 1024, N = 1024;
  __shared__ bf16_t As[128 * 32];
  __shared__ bf16_t Bs[64 * 32];

  const int tid = threadIdx.x;
  const int wave = tid >> 6, lane = tid & 63;
  const int g = lane >> 4, l15 = lane & 15;
  const long m0 = (long)blockIdx.x * 128;
  const long n0 = (long)blockIdx.y * 64;

  const int srow = lane >> 2;
  const int scol = (lane & 3) * 8;

  const int wr = (wave >> 1) * 64;
  const int wc = (wave & 1) * 32;

  f32x4 acc[4][2] = {};

  for (int k0 = 0; k0 < K; k0 += 32) {
    __syncthreads();
#pragma unroll
    for (int c = 0; c < 3; ++c) {
      int idx = wave * 3 + c;            // 0..11 (wave-uniform)
      if (idx < 8) {
        int row = idx * 16 + srow;
        gload_lds16(A + (m0 + row) * K + k0 + scol, (char*)As + idx * 1024);
      } else {
        int row = (idx - 8) * 16 + srow;
        gload_lds16(W + (n0 + row) * K + k0 + scol, (char*)Bs + (idx - 8) * 1024);
      }
    }
    __syncthreads();

    bf16x8 af[4], bfr[2];
#pragma unroll
    for (int i = 0; i < 4; ++i)
      af[i] = *(const bf16x8*)(As + (wr + i * 16 + l15) * 32 + g * 8);
#pragma unroll
    for (int i = 0; i < 2; ++i)
      bfr[i] = *(const bf16x8*)(Bs + (wc + i * 16 + l15) * 32 + g * 8);
    __builtin_amdgcn_s_setprio(1);
#pragma unroll
    for (int mi = 0; mi < 4; ++mi)
#pragma unroll
      for (int ni = 0; ni < 2; ++ni)
        acc[mi][ni] = MFMA16x16x32(af[mi], bfr[ni], acc[mi][ni]);
    __builtin_amdgcn_s_setprio(0);
  }

#pragma unroll
  for (int ni = 0; ni < 2; ++ni) {
    long col = n0 + wc + ni * 16 + l15;
    float bv = bias[col];
#pragma unroll
    for (int mi = 0; mi < 4; ++mi) {
#pragma unroll
      for (int r = 0; r < 4; ++r) {
        long row = m0 + wr + mi * 16 + g * 4 + r;
        out[row * N + col] = acc[mi][ni][r] + bv;
      }
    }
  }
}

// ---------------- Flash attention (R6 attn_fwd5, proven 72.2 us) ----------------
// grid (32 qb x 32 bh), 128 threads (2 waves x 32 q). Double-buffered K/V LDS, no split.
// Per tile t: QK(t) MFMA -> PV(t-1) MFMA (register-only; carried pbP/vaP) -> softmax(t) VALU.
// Mask in LDS (lgkm) so K-prefetch vmcnt queue is never drained mid-loop (R4 lesson).
// NOTE (R9/R12 lesson, twice-measured): launch_bounds arg2 >= 4 on this body forces
// VGPR=64 -> ~400 MB scratch spill. Keep (128, 2).
__global__ __launch_bounds__(128, 2) void attn_fwd5(
    const bf16_t* __restrict__ Qm, const bf16_t* __restrict__ Km,
    const bf16_t* __restrict__ Vm, const float* __restrict__ mask,
    bf16_t* __restrict__ ctx) {
  constexpr int S = 2048, Hs = 1024;
  constexpr float L2E = 1.4426950408889634f;
  // bijective XCD swizzle: 1024 blocks -> 128 consecutive per XCD (4 bh each; K/V 2MB <= L2)
  int id = blockIdx.y * 32 + blockIdx.x;
  int swz = ((id & 7) << 7) | (id >> 3);
  const int qb = swz & 31;
  const int bh = swz >> 5;
  const int b = bh >> 4, h = bh & 15;

  const int tid = threadIdx.x;
  const int wave = tid >> 6, lane = tid & 63;
  const int l31 = lane & 31, hi = lane >> 5;

  __shared__ bf16_t Kb_[2][64 * 64];   // [key][d], 16B-slot XOR swizzled by (key&7)
  __shared__ bf16_t Vb_[2][64 * 64];   // [d][key], 16B-slot XOR swizzled by (d&7)
  __shared__ float Ms[2048];           // mask row (f32)

  const char* Kg = (const char*)(Km + ((long)b * S) * Hs + h * 64);
  const bf16_t* Vg = Vm + ((long)b * S) * Hs + h * 64;
  const float* mrow = mask + b * S;

  // hoisted Q B-fragments: col=q=l31, k-slot d = ks*16 + hi*8 + j
  const long qrow = (long)b * S + qb * 64 + wave * 32 + l31;
  const bf16_t* Qr = Qm + qrow * Hs + h * 64 + hi * 8;
  bf16x8 qB[4];
#pragma unroll
  for (int ks = 0; ks < 4; ++ks) qB[ks] = *(const bf16x8*)(Qr + ks * 16);

  // V staging: thread covers keys 4ka..4ka+3  x  d dq*8..dq*8+7
  const int ka = tid & 15, dq = tid >> 4;
  const bf16_t* Vsrc0 = Vg + (long)(4 * ka) * Hs + dq * 8;

  // K staging: per wave 4 chunks of 1024B (8 rows), pre-swizzled global source
  const int krow_in8 = lane >> 3;
  const int kslot = (lane & 7) ^ krow_in8;

  // ---- prologue: mask + tile 0 ----
#pragma unroll
  for (int c = 0; c < 4; ++c) {
    int ch = wave * 4 + c;
    gload_lds16((const char*)mrow + ch * 1024 + lane * 16, (char*)Ms + ch * 1024);
  }
#pragma unroll
  for (int c = 0; c < 4; ++c) {
    int ch = wave * 4 + c;
    gload_lds16(Kg + (long)(ch * 8 + krow_in8) * (Hs * 2) + kslot * 16,
                (char*)Kb_[0] + ch * 1024);
  }
  int4 v0 = *(const int4*)(Vsrc0);
  int4 v1 = *(const int4*)(Vsrc0 + Hs);
  int4 v2 = *(const int4*)(Vsrc0 + 2 * Hs);
  int4 v3 = *(const int4*)(Vsrc0 + 3 * Hs);
  {
    const u16* p0 = (const u16*)&v0; const u16* p1 = (const u16*)&v1;
    const u16* p2 = (const u16*)&v2; const u16* p3 = (const u16*)&v3;
#pragma unroll
    for (int j = 0; j < 8; ++j) {
      int d = dq * 8 + j;
      int2 w;
      w.x = (int)((unsigned)p0[j] | ((unsigned)p1[j] << 16));
      w.y = (int)((unsigned)p2[j] | ((unsigned)p3[j] << 16));
      *(int2*)((char*)Vb_[0] + d * 128 + ((8 * ka) ^ (j << 4))) = w;
    }
  }
  __syncthreads();

  f32x16 acc0 = {}, acc1 = {};
  float rho = 0.0f, lrun = 0.0f;
  bf16x8 pbP[4] = {};   // packed P(t-1): [st*2+ks2]
  bf16x8 vaP[8] = {};   // V^T frags of tile t-1: [(st*2+ks2)*2+dh]

  for (int t = 0; t < 32; ++t) {
    const int cur = t & 1;
    const char* kb_c = (const char*)Kb_[cur];
    const char* vb_c = (const char*)Vb_[cur];

    // K-fragments for QK (LDS)
    bf16x8 kf0[4], kf1[4];
#pragma unroll
    for (int ks = 0; ks < 4; ++ks)
      kf0[ks] = *(const bf16x8*)(kb_c + l31 * 128 + (((2 * ks + hi) * 16) ^ ((l31 & 7) << 4)));
#pragma unroll
    for (int ks = 0; ks < 4; ++ks) {
      int row = 32 + l31;
      kf1[ks] = *(const bf16x8*)(kb_c + row * 128 + (((2 * ks + hi) * 16) ^ ((row & 7) << 4)));
    }

    // issue next-tile loads early (V reg-loads first, K gload_lds after)
    if (t < 31) {
      const bf16_t* Vs = Vsrc0 + (long)((t + 1) * 64) * Hs;
      v0 = *(const int4*)(Vs);
      v1 = *(const int4*)(Vs + Hs);
      v2 = *(const int4*)(Vs + 2 * Hs);
      v3 = *(const int4*)(Vs + 3 * Hs);
#pragma unroll
      for (int c = 0; c < 4; ++c) {
        int ch = wave * 4 + c;
        gload_lds16(Kg + (long)((t + 1) * 64 + ch * 8 + krow_in8) * (Hs * 2) + kslot * 16,
                    (char*)Kb_[cur ^ 1] + ch * 1024);
      }
    }
    // mask from LDS (lgkm; broadcast within 32-lane halves)
    const float* mbase = Ms + t * 64;
    float4 mk[8];
#pragma unroll
    for (int st = 0; st < 2; ++st)
#pragma unroll
      for (int rg = 0; rg < 4; ++rg)
        mk[st * 4 + rg] = *(const float4*)(mbase + st * 32 + rg * 8 + hi * 4);

    // ---- QK^T: D[key][q] (log2-domain) ----
    f32x16 sc0 = {}, sc1 = {};
    __builtin_amdgcn_s_setprio(1);
#pragma unroll
    for (int ks = 0; ks < 4; ++ks) sc0 = MFMA32x32x16(kf0[ks], qB[ks], sc0);
#pragma unroll
    for (int ks = 0; ks < 4; ++ks) sc1 = MFMA32x32x16(kf1[ks], qB[ks], sc1);
    __builtin_amdgcn_s_setprio(0);

    // ---- PV(t-1): register-only, independent of tile t -> overlaps softmax below ----
    if (t > 0) {
      __builtin_amdgcn_s_setprio(1);
#pragma unroll
      for (int st = 0; st < 2; ++st)
#pragma unroll
        for (int ks2 = 0; ks2 < 2; ++ks2) {
          int i = st * 2 + ks2;
          acc0 = MFMA32x32x16(vaP[i * 2 + 0], pbP[i], acc0);
          acc1 = MFMA32x32x16(vaP[i * 2 + 1], pbP[i], acc1);
        }
      __builtin_amdgcn_s_setprio(0);
    }

    // ---- read V^T frags of tile t (consumed next iteration; latency-tolerant) ----
#pragma unroll
    for (int st = 0; st < 2; ++st)
#pragma unroll
      for (int ks2 = 0; ks2 < 2; ++ks2) {
        int slot = st * 4 + ks2 * 2 + hi;
        int i = st * 2 + ks2;
        vaP[i * 2 + 0] = *(const bf16x8*)(vb_c + l31 * 128 + ((slot * 16) ^ ((l31 & 7) << 4)));
        int d1 = 32 + l31;
        vaP[i * 2 + 1] = *(const bf16x8*)(vb_c + d1 * 128 + ((slot * 16) ^ ((d1 & 7) << 4)));
      }

    // ---- t = r + mask*log2e; row max via 4 chains ----
    float m4[4] = {-1e30f, -1e30f, -1e30f, -1e30f};
#pragma unroll
    for (int st = 0; st < 2; ++st) {
      f32x16& s = st ? sc1 : sc0;
#pragma unroll
      for (int rg = 0; rg < 4; ++rg) {
        float4 m = mk[st * 4 + rg];
#pragma unroll
        for (int i = 0; i < 4; ++i) {
          float v = fmaf(((const float*)&m)[i], L2E, s[rg * 4 + i]);
          s[rg * 4 + i] = v;
          m4[i] = fmaxf(m4[i], v);
        }
      }
    }
    float mt = fmaxf(fmaxf(m4[0], m4[1]), fmaxf(m4[2], m4[3]));
    mt = fmaxf(mt, __shfl_xor(mt, 32, 64));

    // ---- rare rescale: keep exp2 arg <= 24 (acc already holds PV(t-1): consistent) ----
    if (!__all(mt - rho <= 24.0f)) {
      float mw = mt;
#pragma unroll
      for (int off = 1; off < 32; off <<= 1) mw = fmaxf(mw, __shfl_xor(mw, off, 64));
      float fct = exp2_fast(rho - mw);   // uniform
      lrun *= fct;
#pragma unroll
      for (int i = 0; i < 16; ++i) { acc0[i] *= fct; acc1[i] *= fct; }
      rho = mw;
    }
    float rho_u = __builtin_amdgcn_readfirstlane(rho);
    if (rho_u != 0.0f) {
#pragma unroll
      for (int i = 0; i < 16; ++i) { sc0[i] -= rho_u; sc1[i] -= rho_u; }
    }

    // ---- p = exp2(t); sum via 4 chains ----
    float s4[4] = {0.f, 0.f, 0.f, 0.f};
#pragma unroll
    for (int st = 0; st < 2; ++st) {
      f32x16& s = st ? sc1 : sc0;
#pragma unroll
      for (int i = 0; i < 16; ++i) {
        float p = exp2_fast(s[i]);
        s[i] = p;
        s4[i & 3] += p;
      }
    }
    float ls = (s4[0] + s4[1]) + (s4[2] + s4[3]);
    ls += __shfl_xor(ls, 32, 64);
    lrun += ls;

    // ---- pack P(t) -> pbP (consumed next iteration) ----
#pragma unroll
    for (int st = 0; st < 2; ++st) {
      f32x16& s = st ? sc1 : sc0;
      unsigned a0 = pk2(s[0], s[1]),   b0 = pk2(s[4], s[5]);
      unsigned a1 = pk2(s[2], s[3]),   b1 = pk2(s[6], s[7]);
      unsigned a2 = pk2(s[8], s[9]),   b2 = pk2(s[12], s[13]);
      unsigned a3 = pk2(s[10], s[11]), b3 = pk2(s[14], s[15]);
      asm("v_permlane32_swap_b32 %0, %1" : "+v"(a0), "+v"(b0));
      asm("v_permlane32_swap_b32 %0, %1" : "+v"(a1), "+v"(b1));
      asm("v_permlane32_swap_b32 %0, %1" : "+v"(a2), "+v"(b2));
      asm("v_permlane32_swap_b32 %0, %1" : "+v"(a3), "+v"(b3));
      pbP[st * 2 + 0] = mk_frag(a0, a1, b0, b1);   // keys st*32 + 0..15
      pbP[st * 2 + 1] = mk_frag(a2, a3, b2, b3);   // keys st*32 + 16..31
    }

    // ---- write next V tile ----
    if (t < 31) {
      const u16* p0 = (const u16*)&v0; const u16* p1 = (const u16*)&v1;
      const u16* p2 = (const u16*)&v2; const u16* p3 = (const u16*)&v3;
      char* vb_n = (char*)Vb_[cur ^ 1];
#pragma unroll
      for (int j = 0; j < 8; ++j) {
        int d = dq * 8 + j;
        int2 w;
        w.x = (int)((unsigned)p0[j] | ((unsigned)p1[j] << 16));
        w.y = (int)((unsigned)p2[j] | ((unsigned)p3[j] << 16));
        *(int2*)(vb_n + d * 128 + ((8 * ka) ^ (j << 4))) = w;
      }
    }
    __syncthreads();
  }

  // ---- epilogue: flush PV(31) ----
  __builtin_amdgcn_s_setprio(1);
#pragma unroll
  for (int st = 0; st < 2; ++st)
#pragma unroll
    for (int ks2 = 0; ks2 < 2; ++ks2) {
      int i = st * 2 + ks2;
      acc0 = MFMA32x32x16(vaP[i * 2 + 0], pbP[i], acc0);
      acc1 = MFMA32x32x16(vaP[i * 2 + 1], pbP[i], acc1);
    }
  __builtin_amdgcn_s_setprio(0);

  // ---- D2 col=q=l31, row d = dh*32 + (r&3)+8*(r>>2)+4*hi ----
  float inv = 1.0f / lrun;
  bf16_t* cb = ctx + qrow * Hs + h * 64;
#pragma unroll
  for (int dh = 0; dh < 2; ++dh) {
    f32x16& a = dh ? acc1 : acc0;
#pragma unroll
    for (int rg = 0; rg < 4; ++rg) {
      ushort4 o;
      o.x = bits_of((bf16_t)(a[rg * 4 + 0] * inv));
      o.y = bits_of((bf16_t)(a[rg * 4 + 1] * inv));
      o.z = bits_of((bf16_t)(a[rg * 4 + 2] * inv));
      o.w = bits_of((bf16_t)(a[rg * 4 + 3] * inv));
      *(ushort4*)(cb + dh * 32 + rg * 8 + hi * 4) = o;
    }
  }
}

// ---------------- launcher ----------------
extern "C" void kernel_launch(void* const* d_in, const int* in_sizes, int n_in,
                              void* d_out, int out_size, void* d_ws, size_t ws_size,
                              hipStream_t stream) {
  (void)in_sizes; (void)n_in; (void)out_size; (void)ws_size;
  const float* X  = (const float*)d_in[0];
  const float* mask = (const float*)d_in[1];
  const float* Wq = (const float*)d_in[2];
  const float* bq = (const float*)d_in[3];
  const float* Wk = (const float*)d_in[4];
  const float* bk = (const float*)d_in[5];
  const float* Wv = (const float*)d_in[6];
  const float* bv = (const float*)d_in[7];
  const float* Wo = (const float*)d_in[8];
  const float* bo = (const float*)d_in[9];

  char* ws = (char*)d_ws;
  bf16_t* Xb  = (bf16_t*)(ws + 0);          // dead after QKV GEMM
  bf16_t* Wqb = (bf16_t*)(ws + 8388608);
  bf16_t* Wkb = (bf16_t*)(ws + 10485760);
  bf16_t* Wvb = (bf16_t*)(ws + 12582912);
  bf16_t* Wob = (bf16_t*)(ws + 14680064);   // LIVE until O-GEMM
  bf16_t* Qb  = (bf16_t*)(ws + 16777216);
  bf16_t* Kb  = (bf16_t*)(ws + 25165824);
  bf16_t* Vb  = (bf16_t*)(ws + 33554432);
  bf16_t* Cb  = (bf16_t*)(ws + 41943040);   // ctx bf16 (dedicated)

  cvt_all<<<8192, 256, 0, stream>>>((const float4*)X, (const float4*)Wq, (const float4*)Wk,
                                    (const float4*)Wv, (const float4*)Wo, (ushort4*)Xb);

  // QKV projections; Q pre-scaled by 0.125*log2e so attention scores are log2-domain
  const float QSCALE = 0.125f * 1.4426950408889634f;
  dim3 gq(32, 8, 3);
  gemm_bt<<<gq, 256, 0, stream>>>(Xb, Wqb, Wkb, Wvb, bq, bk, bv, Qb, Kb, Vb,
                                  QSCALE, 1.0f, 1.0f);

  // attention (R6 proven structure)
  dim3 ga(32, 32, 1);
  attn_fwd5<<<ga, 128, 0, stream>>>(Qb, Kb, Vb, mask, Cb);

  // output projection -> f32 d_out (128x64 tiles, 512 blocks = 2/CU)
  dim3 go(32, 16, 1);
  gemm_o64<<<go, 256, 0, stream>>>(Cb, Wob, bo, (float*)d_out);
}

// Round 14
// 125.744 us; speedup vs baseline: 1.9845x; 1.0188x over previous
//
#include <hip/hip_runtime.h>
#include <hip/hip_bf16.h>

typedef __bf16 bf16_t;
typedef __bf16 bf16x8 __attribute__((ext_vector_type(8)));
typedef float f32x4 __attribute__((ext_vector_type(4)));
typedef float f32x16 __attribute__((ext_vector_type(16)));
typedef unsigned short u16;

#define DEVI __device__ __forceinline__
#define MFMA16x16x32(A, B, C) __builtin_amdgcn_mfma_f32_16x16x32_bf16(A, B, C, 0, 0, 0)
#define MFMA32x32x16(A, B, C) __builtin_amdgcn_mfma_f32_32x32x16_bf16(A, B, C, 0, 0, 0)

DEVI void gload_lds16(const void* g, void* l) {
  __builtin_amdgcn_global_load_lds(
      (const __attribute__((address_space(1))) void*)g,
      (__attribute__((address_space(3))) void*)l, 16, 0, 0);
}

DEVI u16 bits_of(bf16_t x) { return __builtin_bit_cast(u16, x); }

DEVI unsigned pk2(float lo, float hi) {
  return (unsigned)bits_of((bf16_t)lo) | ((unsigned)bits_of((bf16_t)hi) << 16);
}

DEVI bf16x8 mk_frag(unsigned s0, unsigned s1, unsigned s2, unsigned s3) {
  int4 t;
  t.x = (int)s0; t.y = (int)s1; t.z = (int)s2; t.w = (int)s3;
  return __builtin_bit_cast(bf16x8, t);
}

#if __has_builtin(__builtin_amdgcn_exp2f)
DEVI float exp2_fast(float x) { return __builtin_amdgcn_exp2f(x); }
#else
DEVI float exp2_fast(float x) { return __exp2f(x); }
#endif

// ---------------- fused fp32 -> bf16 conversion: X + 4 weight matrices ----------------
__global__ void cvt_all(const float4* __restrict__ X,
                        const float4* __restrict__ Wq, const float4* __restrict__ Wk,
                        const float4* __restrict__ Wv, const float4* __restrict__ Wo,
                        ushort4* __restrict__ out) {
  int i = blockIdx.x * 256 + threadIdx.x;   // 0 .. 2097151 float4s
  const float4* src;
  int off;
  if (i < 1048576) { src = X; off = i; }
  else {
    int j = i - 1048576;
    int seg = j >> 18;
    off = j & 262143;
    src = (seg == 0) ? Wq : (seg == 1) ? Wk : (seg == 2) ? Wv : Wo;
  }
  float4 v = src[off];
  ushort4 o;
  o.x = bits_of((bf16_t)v.x);
  o.y = bits_of((bf16_t)v.y);
  o.z = bits_of((bf16_t)v.z);
  o.w = bits_of((bf16_t)v.w);
  out[i] = o;
}

// ---------------- QKV GEMM: 128x128 tile, bf16 out (proven ~760 TF) ----------------
__global__ __launch_bounds__(256, 3) void gemm_bt(
    const bf16_t* __restrict__ A,
    const bf16_t* __restrict__ W0, const bf16_t* __restrict__ W1, const bf16_t* __restrict__ W2,
    const float* __restrict__ b0, const float* __restrict__ b1, const float* __restrict__ b2,
    bf16_t* o0, bf16_t* o1, bf16_t* o2, float s0, float s1, float s2) {
  constexpr int K = 1024, N = 1024;
  const int z = blockIdx.z;
  const bf16_t* W = (z == 0) ? W0 : ((z == 1) ? W1 : W2);
  const float* bias = (z == 0) ? b0 : ((z == 1) ? b1 : b2);
  bf16_t* out = (z == 0) ? o0 : ((z == 1) ? o1 : o2);
  const float scale = (z == 0) ? s0 : ((z == 1) ? s1 : s2);

  __shared__ bf16_t As[128 * 32];
  __shared__ bf16_t Bs[128 * 32];

  const int tid = threadIdx.x;
  const int wave = tid >> 6, lane = tid & 63;
  const int g = lane >> 4, l15 = lane & 15;
  const long m0 = (long)blockIdx.x * 128;
  const long n0 = (long)blockIdx.y * 128;

  const int srow = lane >> 2;
  const int scol = (lane & 3) * 8;

  const int wr = (wave >> 1) * 64;
  const int wc = (wave & 1) * 64;

  f32x4 acc[4][4] = {};

  for (int k0 = 0; k0 < K; k0 += 32) {
    __syncthreads();
#pragma unroll
    for (int t = 0; t < 2; ++t) {
      int chunk = wave * 2 + t;
      int row = chunk * 16 + srow;
      gload_lds16(A + (m0 + row) * K + k0 + scol, (char*)As + chunk * 1024);
      gload_lds16(W + (n0 + row) * K + k0 + scol, (char*)Bs + chunk * 1024);
    }
    __syncthreads();

    bf16x8 af[4], bfr[4];
#pragma unroll
    for (int i = 0; i < 4; ++i)
      af[i] = *(const bf16x8*)(As + (wr + i * 16 + l15) * 32 + g * 8);
#pragma unroll
    for (int i = 0; i < 4; ++i)
      bfr[i] = *(const bf16x8*)(Bs + (wc + i * 16 + l15) * 32 + g * 8);
    __builtin_amdgcn_s_setprio(1);
#pragma unroll
    for (int mi = 0; mi < 4; ++mi)
#pragma unroll
      for (int ni = 0; ni < 4; ++ni)
        acc[mi][ni] = MFMA16x16x32(af[mi], bfr[ni], acc[mi][ni]);
    __builtin_amdgcn_s_setprio(0);
  }

#pragma unroll
  for (int ni = 0; ni < 4; ++ni) {
    long col = n0 + wc + ni * 16 + l15;
    float bv = bias[col];
#pragma unroll
    for (int mi = 0; mi < 4; ++mi) {
#pragma unroll
      for (int r = 0; r < 4; ++r) {
        long row = m0 + wr + mi * 16 + g * 4 + r;
        out[row * N + col] = (bf16_t)((acc[mi][ni][r] + bv) * scale);
      }
    }
  }
}

// ---------------- O-projection GEMM: 128x64 tile, f32 out (512 blocks = 2/CU) ----------------
__global__ __launch_bounds__(256, 3) void gemm_o64(
    const bf16_t* __restrict__ A, const bf16_t* __restrict__ W,
    const float* __restrict__ bias, float* __restrict__ out) {
  constexpr int K = 1024, N = 1024;
  __shared__ bf16_t As[128 * 32];
  __shared__ bf16_t Bs[64 * 32];

  const int tid = threadIdx.x;
  const int wave = tid >> 6, lane = tid & 63;
  const int g = lane >> 4, l15 = lane & 15;
  const long m0 = (long)blockIdx.x * 128;
  const long n0 = (long)blockIdx.y * 64;

  const int srow = lane >> 2;
  const int scol = (lane & 3) * 8;

  const int wr = (wave >> 1) * 64;
  const int wc = (wave & 1) * 32;

  f32x4 acc[4][2] = {};

  for (int k0 = 0; k0 < K; k0 += 32) {
    __syncthreads();
#pragma unroll
    for (int c = 0; c < 3; ++c) {
      int idx = wave * 3 + c;            // 0..11 (wave-uniform)
      if (idx < 8) {
        int row = idx * 16 + srow;
        gload_lds16(A + (m0 + row) * K + k0 + scol, (char*)As + idx * 1024);
      } else {
        int row = (idx - 8) * 16 + srow;
        gload_lds16(W + (n0 + row) * K + k0 + scol, (char*)Bs + (idx - 8) * 1024);
      }
    }
    __syncthreads();

    bf16x8 af[4], bfr[2];
#pragma unroll
    for (int i = 0; i < 4; ++i)
      af[i] = *(const bf16x8*)(As + (wr + i * 16 + l15) * 32 + g * 8);
#pragma unroll
    for (int i = 0; i < 2; ++i)
      bfr[i] = *(const bf16x8*)(Bs + (wc + i * 16 + l15) * 32 + g * 8);
    __builtin_amdgcn_s_setprio(1);
#pragma unroll
    for (int mi = 0; mi < 4; ++mi)
#pragma unroll
      for (int ni = 0; ni < 2; ++ni)
        acc[mi][ni] = MFMA16x16x32(af[mi], bfr[ni], acc[mi][ni]);
    __builtin_amdgcn_s_setprio(0);
  }

#pragma unroll
  for (int ni = 0; ni < 2; ++ni) {
    long col = n0 + wc + ni * 16 + l15;
    float bv = bias[col];
#pragma unroll
    for (int mi = 0; mi < 4; ++mi) {
#pragma unroll
      for (int r = 0; r < 4; ++r) {
        long row = m0 + wr + mi * 16 + g * 4 + r;
        out[row * N + col] = acc[mi][ni][r] + bv;
      }
    }
  }
}

// ---------------- Flash attention: QBLK=128, 4 waves, staging amortized ----------------
// grid (16 qb x 32 bh) = 512 blocks x 256 threads (4 waves x 32 q) = 2048 waves = 2/SIMD
// (same occupancy as R6) -- the change is staging amortization: K/V/mask staged once per
// block now serves 128 q rows (4 waves) instead of 64 (2 waves): per wave per tile,
// 2 K gload_lds (was 4), 4 int2 V loads (was 4 int4), 4 packed LDS writes (was 8); K/V
// L2/HBM re-reads halve (16 blocks/bh). Compute path byte-identical to R6's attn_fwd5.
// launch_bounds(256, 2): VGPR budget 256 -- R9/R12 rule (arg2>=4 forces 64 VGPR + spill).
__global__ __launch_bounds__(256, 2) void attn_fwd10(
    const bf16_t* __restrict__ Qm, const bf16_t* __restrict__ Km,
    const bf16_t* __restrict__ Vm, const float* __restrict__ mask,
    bf16_t* __restrict__ ctx) {
  constexpr int S = 2048, Hs = 1024;
  constexpr float L2E = 1.4426950408889634f;
  // bijective XCD swizzle: 512 blocks -> 64 consecutive per XCD (4 bh each; K/V 2MB <= L2)
  int id = blockIdx.y * 16 + blockIdx.x;
  int swz = ((id & 7) << 6) | (id >> 3);
  const int qb = swz & 15;
  const int bh = swz >> 4;
  const int b = bh >> 4, h = bh & 15;

  const int tid = threadIdx.x;          // 0..255
  const int wave = tid >> 6, lane = tid & 63;
  const int l31 = lane & 31, hi = lane >> 5;

  __shared__ bf16_t Kb_[2][64 * 64];   // [key][d], 16B-slot XOR swizzled by (key&7)
  __shared__ bf16_t Vb_[2][64 * 64];   // [d][key], 16B-slot XOR swizzled by (d&7)
  __shared__ float Ms[2048];           // mask row (f32)

  const char* Kg = (const char*)(Km + ((long)b * S) * Hs + h * 64);
  const bf16_t* Vg = Vm + ((long)b * S) * Hs + h * 64;
  const float* mrow = mask + b * S;

  // hoisted Q B-fragments: col=q=l31, k-slot d = ks*16 + hi*8 + j
  const long qrow = (long)b * S + qb * 128 + wave * 32 + l31;
  const bf16_t* Qr = Qm + qrow * Hs + h * 64 + hi * 8;
  bf16x8 qB[4];
#pragma unroll
  for (int ks = 0; ks < 4; ++ks) qB[ks] = *(const bf16x8*)(Qr + ks * 16);

  // V staging: thread covers keys 4ka..4ka+3  x  d dq*4..dq*4+3 (256 threads)
  const int ka = tid & 15, dq = tid >> 4;   // dq 0..15
  const bf16_t* Vsrc0 = Vg + (long)(4 * ka) * Hs + dq * 4;

  // K staging: 8 chunks of 1024B (8 rows), 2 per wave; pre-swizzled global source
  const int krow_in8 = lane >> 3;
  const int kslot = (lane & 7) ^ krow_in8;

  // ---- prologue: mask (2 chunks/wave) + tile 0 ----
#pragma unroll
  for (int c = 0; c < 2; ++c) {
    int ch = wave * 2 + c;
    gload_lds16((const char*)mrow + ch * 1024 + lane * 16, (char*)Ms + ch * 1024);
  }
#pragma unroll
  for (int c = 0; c < 2; ++c) {
    int ch = wave * 2 + c;
    gload_lds16(Kg + (long)(ch * 8 + krow_in8) * (Hs * 2) + kslot * 16,
                (char*)Kb_[0] + ch * 1024);
  }
  int2 v0 = *(const int2*)(Vsrc0);
  int2 v1 = *(const int2*)(Vsrc0 + Hs);
  int2 v2 = *(const int2*)(Vsrc0 + 2 * Hs);
  int2 v3 = *(const int2*)(Vsrc0 + 3 * Hs);
  {
    const u16* p0 = (const u16*)&v0; const u16* p1 = (const u16*)&v1;
    const u16* p2 = (const u16*)&v2; const u16* p3 = (const u16*)&v3;
#pragma unroll
    for (int j = 0; j < 4; ++j) {
      int d = dq * 4 + j;
      int2 w;
      w.x = (int)((unsigned)p0[j] | ((unsigned)p1[j] << 16));
      w.y = (int)((unsigned)p2[j] | ((unsigned)p3[j] << 16));
      *(int2*)((char*)Vb_[0] + d * 128 + ((8 * ka) ^ ((d & 7) << 4))) = w;
    }
  }
  __syncthreads();

  f32x16 acc0 = {}, acc1 = {};
  float rho = 0.0f, lrun = 0.0f;
  bf16x8 pbP[4] = {};   // packed P(t-1): [st*2+ks2]
  bf16x8 vaP[8] = {};   // V^T frags of tile t-1: [(st*2+ks2)*2+dh]

  for (int t = 0; t < 32; ++t) {
    const int cur = t & 1;
    const char* kb_c = (const char*)Kb_[cur];
    const char* vb_c = (const char*)Vb_[cur];

    // K-fragments for QK (LDS)
    bf16x8 kf0[4], kf1[4];
#pragma unroll
    for (int ks = 0; ks < 4; ++ks)
      kf0[ks] = *(const bf16x8*)(kb_c + l31 * 128 + (((2 * ks + hi) * 16) ^ ((l31 & 7) << 4)));
#pragma unroll
    for (int ks = 0; ks < 4; ++ks) {
      int row = 32 + l31;
      kf1[ks] = *(const bf16x8*)(kb_c + row * 128 + (((2 * ks + hi) * 16) ^ ((row & 7) << 4)));
    }

    // issue next-tile loads early (V reg-loads first, K gload_lds after)
    if (t < 31) {
      const bf16_t* Vs = Vsrc0 + (long)((t + 1) * 64) * Hs;
      v0 = *(const int2*)(Vs);
      v1 = *(const int2*)(Vs + Hs);
      v2 = *(const int2*)(Vs + 2 * Hs);
      v3 = *(const int2*)(Vs + 3 * Hs);
#pragma unroll
      for (int c = 0; c < 2; ++c) {
        int ch = wave * 2 + c;
        gload_lds16(Kg + (long)((t + 1) * 64 + ch * 8 + krow_in8) * (Hs * 2) + kslot * 16,
                    (char*)Kb_[cur ^ 1] + ch * 1024);
      }
    }
    // mask from LDS (lgkm; broadcast within 32-lane halves)
    const float* mbase = Ms + t * 64;
    float4 mk[8];
#pragma unroll
    for (int st = 0; st < 2; ++st)
#pragma unroll
      for (int rg = 0; rg < 4; ++rg)
        mk[st * 4 + rg] = *(const float4*)(mbase + st * 32 + rg * 8 + hi * 4);

    // ---- QK^T: D[key][q] (log2-domain) ----
    f32x16 sc0 = {}, sc1 = {};
    __builtin_amdgcn_s_setprio(1);
#pragma unroll
    for (int ks = 0; ks < 4; ++ks) sc0 = MFMA32x32x16(kf0[ks], qB[ks], sc0);
#pragma unroll
    for (int ks = 0; ks < 4; ++ks) sc1 = MFMA32x32x16(kf1[ks], qB[ks], sc1);
    __builtin_amdgcn_s_setprio(0);

    // ---- PV(t-1): register-only, independent of tile t -> overlaps softmax below ----
    if (t > 0) {
      __builtin_amdgcn_s_setprio(1);
#pragma unroll
      for (int st = 0; st < 2; ++st)
#pragma unroll
        for (int ks2 = 0; ks2 < 2; ++ks2) {
          int i = st * 2 + ks2;
          acc0 = MFMA32x32x16(vaP[i * 2 + 0], pbP[i], acc0);
          acc1 = MFMA32x32x16(vaP[i * 2 + 1], pbP[i], acc1);
        }
      __builtin_amdgcn_s_setprio(0);
    }

    // ---- read V^T frags of tile t (consumed next iteration; latency-tolerant) ----
#pragma unroll
    for (int st = 0; st < 2; ++st)
#pragma unroll
      for (int ks2 = 0; ks2 < 2; ++ks2) {
        int slot = st * 4 + ks2 * 2 + hi;
        int i = st * 2 + ks2;
        vaP[i * 2 + 0] = *(const bf16x8*)(vb_c + l31 * 128 + ((slot * 16) ^ ((l31 & 7) << 4)));
        int d1 = 32 + l31;
        vaP[i * 2 + 1] = *(const bf16x8*)(vb_c + d1 * 128 + ((slot * 16) ^ ((d1 & 7) << 4)));
      }

    // ---- t = r + mask*log2e; row max via 4 chains ----
    float m4[4] = {-1e30f, -1e30f, -1e30f, -1e30f};
#pragma unroll
    for (int st = 0; st < 2; ++st) {
      f32x16& s = st ? sc1 : sc0;
#pragma unroll
      for (int rg = 0; rg < 4; ++rg) {
        float4 m = mk[st * 4 + rg];
#pragma unroll
        for (int i = 0; i < 4; ++i) {
          float v = fmaf(((const float*)&m)[i], L2E, s[rg * 4 + i]);
          s[rg * 4 + i] = v;
          m4[i] = fmaxf(m4[i], v);
        }
      }
    }
    float mt = fmaxf(fmaxf(m4[0], m4[1]), fmaxf(m4[2], m4[3]));
    mt = fmaxf(mt, __shfl_xor(mt, 32, 64));

    // ---- rare rescale: keep exp2 arg <= 24 (acc already holds PV(t-1): consistent) ----
    if (!__all(mt - rho <= 24.0f)) {
      float mw = mt;
#pragma unroll
      for (int off = 1; off < 32; off <<= 1) mw = fmaxf(mw, __shfl_xor(mw, off, 64));
      float fct = exp2_fast(rho - mw);   // uniform
      lrun *= fct;
#pragma unroll
      for (int i = 0; i < 16; ++i) { acc0[i] *= fct; acc1[i] *= fct; }
      rho = mw;
    }
    float rho_u = __builtin_amdgcn_readfirstlane(rho);
    if (rho_u != 0.0f) {
#pragma unroll
      for (int i = 0; i < 16; ++i) { sc0[i] -= rho_u; sc1[i] -= rho_u; }
    }

    // ---- p = exp2(t); sum via 4 chains ----
    float s4[4] = {0.f, 0.f, 0.f, 0.f};
#pragma unroll
    for (int st = 0; st < 2; ++st) {
      f32x16& s = st ? sc1 : sc0;
#pragma unroll
      for (int i = 0; i < 16; ++i) {
        float p = exp2_fast(s[i]);
        s[i] = p;
        s4[i & 3] += p;
      }
    }
    float ls = (s4[0] + s4[1]) + (s4[2] + s4[3]);
    ls += __shfl_xor(ls, 32, 64);
    lrun += ls;

    // ---- pack P(t) -> pbP (consumed next iteration) ----
#pragma unroll
    for (int st = 0; st < 2; ++st) {
      f32x16& s = st ? sc1 : sc0;
      unsigned a0 = pk2(s[0], s[1]),   b0 = pk2(s[4], s[5]);
      unsigned a1 = pk2(s[2], s[3]),   b1 = pk2(s[6], s[7]);
      unsigned a2 = pk2(s[8], s[9]),   b2 = pk2(s[12], s[13]);
      unsigned a3 = pk2(s[10], s[11]), b3 = pk2(s[14], s[15]);
      asm("v_permlane32_swap_b32 %0, %1" : "+v"(a0), "+v"(b0));
      asm("v_permlane32_swap_b32 %0, %1" : "+v"(a1), "+v"(b1));
      asm("v_permlane32_swap_b32 %0, %1" : "+v"(a2), "+v"(b2));
      asm("v_permlane32_swap_b32 %0, %1" : "+v"(a3), "+v"(b3));
      pbP[st * 2 + 0] = mk_frag(a0, a1, b0, b1);   // keys st*32 + 0..15
      pbP[st * 2 + 1] = mk_frag(a2, a3, b2, b3);   // keys st*32 + 16..31
    }

    // ---- write next V tile ----
    if (t < 31) {
      const u16* p0 = (const u16*)&v0; const u16* p1 = (const u16*)&v1;
      const u16* p2 = (const u16*)&v2; const u16* p3 = (const u16*)&v3;
      char* vb_n = (char*)Vb_[cur ^ 1];
#pragma unroll
      for (int j = 0; j < 4; ++j) {
        int d = dq * 4 + j;
        int2 w;
        w.x = (int)((unsigned)p0[j] | ((unsigned)p1[j] << 16));
        w.y = (int)((unsigned)p2[j] | ((unsigned)p3[j] << 16));
        *(int2*)(vb_n + d * 128 + ((8 * ka) ^ ((d & 7) << 4))) = w;
      }
    }
    __syncthreads();
  }

  // ---- epilogue: flush PV(31) ----
  __builtin_amdgcn_s_setprio(1);
#pragma unroll
  for (int st = 0; st < 2; ++st)
#pragma unroll
    for (int ks2 = 0; ks2 < 2; ++ks2) {
      int i = st * 2 + ks2;
      acc0 = MFMA32x32x16(vaP[i * 2 + 0], pbP[i], acc0);
      acc1 = MFMA32x32x16(vaP[i * 2 + 1], pbP[i], acc1);
    }
  __builtin_amdgcn_s_setprio(0);

  // ---- D2 col=q=l31, row d = dh*32 + (r&3)+8*(r>>2)+4*hi ----
  float inv = 1.0f / lrun;
  bf16_t* cb = ctx + qrow * Hs + h * 64;
#pragma unroll
  for (int dh = 0; dh < 2; ++dh) {
    f32x16& a = dh ? acc1 : acc0;
#pragma unroll
    for (int rg = 0; rg < 4; ++rg) {
      ushort4 o;
      o.x = bits_of((bf16_t)(a[rg * 4 + 0] * inv));
      o.y = bits_of((bf16_t)(a[rg * 4 + 1] * inv));
      o.z = bits_of((bf16_t)(a[rg * 4 + 2] * inv));
      o.w = bits_of((bf16_t)(a[rg * 4 + 3] * inv));
      *(ushort4*)(cb + dh * 32 + rg * 8 + hi * 4) = o;
    }
  }
}

// ---------------- launcher ----------------
extern "C" void kernel_launch(void* const* d_in, const int* in_sizes, int n_in,
                              void* d_out, int out_size, void* d_ws, size_t ws_size,
                              hipStream_t stream) {
  (void)in_sizes; (void)n_in; (void)out_size; (void)ws_size;
  const float* X  = (const float*)d_in[0];
  const float* mask = (const float*)d_in[1];
  const float* Wq = (const float*)d_in[2];
  const float* bq = (const float*)d_in[3];
  const float* Wk = (const float*)d_in[4];
  const float* bk = (const float*)d_in[5];
  const float* Wv = (const float*)d_in[6];
  const float* bv = (const float*)d_in[7];
  const float* Wo = (const float*)d_in[8];
  const float* bo = (const float*)d_in[9];

  char* ws = (char*)d_ws;
  bf16_t* Xb  = (bf16_t*)(ws + 0);          // dead after QKV GEMM
  bf16_t* Wqb = (bf16_t*)(ws + 8388608);
  bf16_t* Wkb = (bf16_t*)(ws + 10485760);
  bf16_t* Wvb = (bf16_t*)(ws + 12582912);
  bf16_t* Wob = (bf16_t*)(ws + 14680064);   // LIVE until O-GEMM
  bf16_t* Qb  = (bf16_t*)(ws + 16777216);
  bf16_t* Kb  = (bf16_t*)(ws + 25165824);
  bf16_t* Vb  = (bf16_t*)(ws + 33554432);
  bf16_t* Cb  = (bf16_t*)(ws + 41943040);   // ctx bf16 (dedicated)

  cvt_all<<<8192, 256, 0, stream>>>((const float4*)X, (const float4*)Wq, (const float4*)Wk,
                                    (const float4*)Wv, (const float4*)Wo, (ushort4*)Xb);

  // QKV projections; Q pre-scaled by 0.125*log2e so attention scores are log2-domain
  const float QSCALE = 0.125f * 1.4426950408889634f;
  dim3 gq(32, 8, 3);
  gemm_bt<<<gq, 256, 0, stream>>>(Xb, Wqb, Wkb, Wvb, bq, bk, bv, Qb, Kb, Vb,
                                  QSCALE, 1.0f, 1.0f);

  // attention (QBLK=128, 4-wave staging amortization)
  dim3 ga(16, 32, 1);
  attn_fwd10<<<ga, 256, 0, stream>>>(Qb, Kb, Vb, mask, Cb);

  // output projection -> f32 d_out (128x64 tiles, 512 blocks = 2/CU)
  dim3 go(32, 16, 1);
  gemm_o64<<<go, 256, 0, stream>>>(Cb, Wob, bo, (float*)d_out);
}

// Round 15
// 122.445 us; speedup vs baseline: 2.0380x; 1.0269x over previous
//
#include <hip/hip_runtime.h>
#include <hip/hip_bf16.h>

typedef __bf16 bf16_t;
typedef __bf16 bf16x8 __attribute__((ext_vector_type(8)));
typedef float f32x4 __attribute__((ext_vector_type(4)));
typedef float f32x16 __attribute__((ext_vector_type(16)));
typedef unsigned short u16;

#define DEVI __device__ __forceinline__
#define MFMA16x16x32(A, B, C) __builtin_amdgcn_mfma_f32_16x16x32_bf16(A, B, C, 0, 0, 0)
#define MFMA32x32x16(A, B, C) __builtin_amdgcn_mfma_f32_32x32x16_bf16(A, B, C, 0, 0, 0)

DEVI void gload_lds16(const void* g, void* l) {
  __builtin_amdgcn_global_load_lds(
      (const __attribute__((address_space(1))) void*)g,
      (__attribute__((address_space(3))) void*)l, 16, 0, 0);
}

DEVI u16 bits_of(bf16_t x) { return __builtin_bit_cast(u16, x); }

DEVI unsigned pk2(float lo, float hi) {
  return (unsigned)bits_of((bf16_t)lo) | ((unsigned)bits_of((bf16_t)hi) << 16);
}

DEVI bf16x8 mk_frag(unsigned s0, unsigned s1, unsigned s2, unsigned s3) {
  int4 t;
  t.x = (int)s0; t.y = (int)s1; t.z = (int)s2; t.w = (int)s3;
  return __builtin_bit_cast(bf16x8, t);
}

#if __has_builtin(__builtin_amdgcn_exp2f)
DEVI float exp2_fast(float x) { return __builtin_amdgcn_exp2f(x); }
#else
DEVI float exp2_fast(float x) { return __exp2f(x); }
#endif

// ---------------- fused fp32 -> bf16 conversion: X + 4 weight matrices ----------------
__global__ void cvt_all(const float4* __restrict__ X,
                        const float4* __restrict__ Wq, const float4* __restrict__ Wk,
                        const float4* __restrict__ Wv, const float4* __restrict__ Wo,
                        ushort4* __restrict__ out) {
  int i = blockIdx.x * 256 + threadIdx.x;   // 0 .. 2097151 float4s
  const float4* src;
  int off;
  if (i < 1048576) { src = X; off = i; }
  else {
    int j = i - 1048576;
    int seg = j >> 18;
    off = j & 262143;
    src = (seg == 0) ? Wq : (seg == 1) ? Wk : (seg == 2) ? Wv : Wo;
  }
  float4 v = src[off];
  ushort4 o;
  o.x = bits_of((bf16_t)v.x);
  o.y = bits_of((bf16_t)v.y);
  o.z = bits_of((bf16_t)v.z);
  o.w = bits_of((bf16_t)v.w);
  out[i] = o;
}

// ---------------- QKV GEMM: 128x128 tile, bf16 out (proven ~760 TF) ----------------
__global__ __launch_bounds__(256, 3) void gemm_bt(
    const bf16_t* __restrict__ A,
    const bf16_t* __restrict__ W0, const bf16_t* __restrict__ W1, const bf16_t* __restrict__ W2,
    const float* __restrict__ b0, const float* __restrict__ b1, const float* __restrict__ b2,
    bf16_t* o0, bf16_t* o1, bf16_t* o2, float s0, float s1, float s2) {
  constexpr int K = 1024, N = 1024;
  const int z = blockIdx.z;
  const bf16_t* W = (z == 0) ? W0 : ((z == 1) ? W1 : W2);
  const float* bias = (z == 0) ? b0 : ((z == 1) ? b1 : b2);
  bf16_t* out = (z == 0) ? o0 : ((z == 1) ? o1 : o2);
  const float scale = (z == 0) ? s0 : ((z == 1) ? s1 : s2);

  __shared__ bf16_t As[128 * 32];
  __shared__ bf16_t Bs[128 * 32];

  const int tid = threadIdx.x;
  const int wave = tid >> 6, lane = tid & 63;
  const int g = lane >> 4, l15 = lane & 15;
  const long m0 = (long)blockIdx.x * 128;
  const long n0 = (long)blockIdx.y * 128;

  const int srow = lane >> 2;
  const int scol = (lane & 3) * 8;

  const int wr = (wave >> 1) * 64;
  const int wc = (wave & 1) * 64;

  f32x4 acc[4][4] = {};

  for (int k0 = 0; k0 < K; k0 += 32) {
    __syncthreads();
#pragma unroll
    for (int t = 0; t < 2; ++t) {
      int chunk = wave * 2 + t;
      int row = chunk * 16 + srow;
      gload_lds16(A + (m0 + row) * K + k0 + scol, (char*)As + chunk * 1024);
      gload_lds16(W + (n0 + row) * K + k0 + scol, (char*)Bs + chunk * 1024);
    }
    __syncthreads();

    bf16x8 af[4], bfr[4];
#pragma unroll
    for (int i = 0; i < 4; ++i)
      af[i] = *(const bf16x8*)(As + (wr + i * 16 + l15) * 32 + g * 8);
#pragma unroll
    for (int i = 0; i < 4; ++i)
      bfr[i] = *(const bf16x8*)(Bs + (wc + i * 16 + l15) * 32 + g * 8);
    __builtin_amdgcn_s_setprio(1);
#pragma unroll
    for (int mi = 0; mi < 4; ++mi)
#pragma unroll
      for (int ni = 0; ni < 4; ++ni)
        acc[mi][ni] = MFMA16x16x32(af[mi], bfr[ni], acc[mi][ni]);
    __builtin_amdgcn_s_setprio(0);
  }

#pragma unroll
  for (int ni = 0; ni < 4; ++ni) {
    long col = n0 + wc + ni * 16 + l15;
    float bv = bias[col];
#pragma unroll
    for (int mi = 0; mi < 4; ++mi) {
#pragma unroll
      for (int r = 0; r < 4; ++r) {
        long row = m0 + wr + mi * 16 + g * 4 + r;
        out[row * N + col] = (bf16_t)((acc[mi][ni][r] + bv) * scale);
      }
    }
  }
}

// ---------------- O-projection GEMM: 128x64 tile, f32 out (512 blocks = 2/CU) ----------------
__global__ __launch_bounds__(256, 3) void gemm_o64(
    const bf16_t* __restrict__ A, const bf16_t* __restrict__ W,
    const float* __restrict__ bias, float* __restrict__ out) {
  constexpr int K = 1024, N = 1024;
  __shared__ bf16_t As[128 * 32];
  __shared__ bf16_t Bs[64 * 32];

  const int tid = threadIdx.x;
  const int wave = tid >> 6, lane = tid & 63;
  const int g = lane >> 4, l15 = lane & 15;
  const long m0 = (long)blockIdx.x * 128;
  const long n0 = (long)blockIdx.y * 64;

  const int srow = lane >> 2;
  const int scol = (lane & 3) * 8;

  const int wr = (wave >> 1) * 64;
  const int wc = (wave & 1) * 32;

  f32x4 acc[4][2] = {};

  for (int k0 = 0; k0 < K; k0 += 32) {
    __syncthreads();
#pragma unroll
    for (int c = 0; c < 3; ++c) {
      int idx = wave * 3 + c;            // 0..11 (wave-uniform)
      if (idx < 8) {
        int row = idx * 16 + srow;
        gload_lds16(A + (m0 + row) * K + k0 + scol, (char*)As + idx * 1024);
      } else {
        int row = (idx - 8) * 16 + srow;
        gload_lds16(W + (n0 + row) * K + k0 + scol, (char*)Bs + (idx - 8) * 1024);
      }
    }
    __syncthreads();

    bf16x8 af[4], bfr[2];
#pragma unroll
    for (int i = 0; i < 4; ++i)
      af[i] = *(const bf16x8*)(As + (wr + i * 16 + l15) * 32 + g * 8);
#pragma unroll
    for (int i = 0; i < 2; ++i)
      bfr[i] = *(const bf16x8*)(Bs + (wc + i * 16 + l15) * 32 + g * 8);
    __builtin_amdgcn_s_setprio(1);
#pragma unroll
    for (int mi = 0; mi < 4; ++mi)
#pragma unroll
      for (int ni = 0; ni < 2; ++ni)
        acc[mi][ni] = MFMA16x16x32(af[mi], bfr[ni], acc[mi][ni]);
    __builtin_amdgcn_s_setprio(0);
  }

#pragma unroll
  for (int ni = 0; ni < 2; ++ni) {
    long col = n0 + wc + ni * 16 + l15;
    float bv = bias[col];
#pragma unroll
    for (int mi = 0; mi < 4; ++mi) {
#pragma unroll
      for (int r = 0; r < 4; ++r) {
        long row = m0 + wr + mi * 16 + g * 4 + r;
        out[row * N + col] = acc[mi][ni][r] + bv;
      }
    }
  }
}

// ---------------- Flash attention: QBLK=256, 8 waves, staging amortized 2x more ----------
// grid (8 qb x 32 bh) = 256 blocks x 512 threads (8 waves x 32 q) = 2048 waves = 2/SIMD.
// R14 lever extrapolated: per wave per tile now 1 K gload_lds (was 2), 2 int2 V loads
// (was 4), 4 int packed writes; K/V L2 re-reads halve again (8 blocks/bh). Compute body
// byte-identical to R14. launch_bounds(512,2) -> k = 2*4/8 = 1 block/CU, VGPR budget 256
// (R9/R12 rule: no aggressive bound). Known trade: 1 block/CU = no cross-block barrier
// overlap (R14 had one other block) -- testing whether amortization > overlap extrapolates.
__global__ __launch_bounds__(512, 2) void attn_fwd11(
    const bf16_t* __restrict__ Qm, const bf16_t* __restrict__ Km,
    const bf16_t* __restrict__ Vm, const float* __restrict__ mask,
    bf16_t* __restrict__ ctx) {
  constexpr int S = 2048, Hs = 1024;
  constexpr float L2E = 1.4426950408889634f;
  // bijective XCD swizzle: 256 blocks -> 32 consecutive per XCD (4 bh x 8 qb each)
  int id = blockIdx.y * 8 + blockIdx.x;
  int swz = ((id & 7) << 5) | (id >> 3);
  const int qb = swz & 7;
  const int bh = swz >> 3;
  const int b = bh >> 4, h = bh & 15;

  const int tid = threadIdx.x;          // 0..511
  const int wave = tid >> 6, lane = tid & 63;
  const int l31 = lane & 31, hi = lane >> 5;

  __shared__ bf16_t Kb_[2][64 * 64];   // [key][d], 16B-slot XOR swizzled by (key&7)
  __shared__ bf16_t Vb_[2][64 * 64];   // [d][key], 16B-slot XOR swizzled by (d&7)
  __shared__ float Ms[2048];           // mask row (f32)

  const char* Kg = (const char*)(Km + ((long)b * S) * Hs + h * 64);
  const bf16_t* Vg = Vm + ((long)b * S) * Hs + h * 64;
  const float* mrow = mask + b * S;

  // hoisted Q B-fragments: col=q=l31, k-slot d = ks*16 + hi*8 + j
  const long qrow = (long)b * S + qb * 256 + wave * 32 + l31;
  const bf16_t* Qr = Qm + qrow * Hs + h * 64 + hi * 8;
  bf16x8 qB[4];
#pragma unroll
  for (int ks = 0; ks < 4; ++ks) qB[ks] = *(const bf16x8*)(Qr + ks * 16);

  // V staging: thread covers keys {2ka2, 2ka2+1} x d dq*4..dq*4+3 (512 threads)
  const int ka2 = tid & 31, dq = tid >> 5;   // dq 0..15
  const bf16_t* Vsrc0 = Vg + (long)(2 * ka2) * Hs + dq * 4;

  // K staging: 8 chunks of 1024B (8 rows), 1 per wave; pre-swizzled global source
  const int krow_in8 = lane >> 3;
  const int kslot = (lane & 7) ^ krow_in8;

  // ---- prologue: mask (1 chunk/wave) + tile 0 ----
  gload_lds16((const char*)mrow + wave * 1024 + lane * 16, (char*)Ms + wave * 1024);
  gload_lds16(Kg + (long)(wave * 8 + krow_in8) * (Hs * 2) + kslot * 16,
              (char*)Kb_[0] + wave * 1024);
  int2 v0 = *(const int2*)(Vsrc0);
  int2 v1 = *(const int2*)(Vsrc0 + Hs);
  {
    const u16* p0 = (const u16*)&v0; const u16* p1 = (const u16*)&v1;
#pragma unroll
    for (int j = 0; j < 4; ++j) {
      int d = dq * 4 + j;
      int w = (int)((unsigned)p0[j] | ((unsigned)p1[j] << 16));
      *(int*)((char*)Vb_[0] + d * 128 + ((4 * ka2) ^ ((d & 7) << 4))) = w;
    }
  }
  __syncthreads();

  f32x16 acc0 = {}, acc1 = {};
  float rho = 0.0f, lrun = 0.0f;
  bf16x8 pbP[4] = {};   // packed P(t-1): [st*2+ks2]
  bf16x8 vaP[8] = {};   // V^T frags of tile t-1: [(st*2+ks2)*2+dh]

  for (int t = 0; t < 32; ++t) {
    const int cur = t & 1;
    const char* kb_c = (const char*)Kb_[cur];
    const char* vb_c = (const char*)Vb_[cur];

    // K-fragments for QK (LDS)
    bf16x8 kf0[4], kf1[4];
#pragma unroll
    for (int ks = 0; ks < 4; ++ks)
      kf0[ks] = *(const bf16x8*)(kb_c + l31 * 128 + (((2 * ks + hi) * 16) ^ ((l31 & 7) << 4)));
#pragma unroll
    for (int ks = 0; ks < 4; ++ks) {
      int row = 32 + l31;
      kf1[ks] = *(const bf16x8*)(kb_c + row * 128 + (((2 * ks + hi) * 16) ^ ((row & 7) << 4)));
    }

    // issue next-tile loads early (V reg-loads first, K gload_lds after)
    if (t < 31) {
      const bf16_t* Vs = Vsrc0 + (long)((t + 1) * 64) * Hs;
      v0 = *(const int2*)(Vs);
      v1 = *(const int2*)(Vs + Hs);
      gload_lds16(Kg + (long)((t + 1) * 64 + wave * 8 + krow_in8) * (Hs * 2) + kslot * 16,
                  (char*)Kb_[cur ^ 1] + wave * 1024);
    }
    // mask from LDS (lgkm; broadcast within 32-lane halves)
    const float* mbase = Ms + t * 64;
    float4 mk[8];
#pragma unroll
    for (int st = 0; st < 2; ++st)
#pragma unroll
      for (int rg = 0; rg < 4; ++rg)
        mk[st * 4 + rg] = *(const float4*)(mbase + st * 32 + rg * 8 + hi * 4);

    // ---- QK^T: D[key][q] (log2-domain) ----
    f32x16 sc0 = {}, sc1 = {};
    __builtin_amdgcn_s_setprio(1);
#pragma unroll
    for (int ks = 0; ks < 4; ++ks) sc0 = MFMA32x32x16(kf0[ks], qB[ks], sc0);
#pragma unroll
    for (int ks = 0; ks < 4; ++ks) sc1 = MFMA32x32x16(kf1[ks], qB[ks], sc1);
    __builtin_amdgcn_s_setprio(0);

    // ---- PV(t-1): register-only, independent of tile t -> overlaps softmax below ----
    if (t > 0) {
      __builtin_amdgcn_s_setprio(1);
#pragma unroll
      for (int st = 0; st < 2; ++st)
#pragma unroll
        for (int ks2 = 0; ks2 < 2; ++ks2) {
          int i = st * 2 + ks2;
          acc0 = MFMA32x32x16(vaP[i * 2 + 0], pbP[i], acc0);
          acc1 = MFMA32x32x16(vaP[i * 2 + 1], pbP[i], acc1);
        }
      __builtin_amdgcn_s_setprio(0);
    }

    // ---- read V^T frags of tile t (consumed next iteration; latency-tolerant) ----
#pragma unroll
    for (int st = 0; st < 2; ++st)
#pragma unroll
      for (int ks2 = 0; ks2 < 2; ++ks2) {
        int slot = st * 4 + ks2 * 2 + hi;
        int i = st * 2 + ks2;
        vaP[i * 2 + 0] = *(const bf16x8*)(vb_c + l31 * 128 + ((slot * 16) ^ ((l31 & 7) << 4)));
        int d1 = 32 + l31;
        vaP[i * 2 + 1] = *(const bf16x8*)(vb_c + d1 * 128 + ((slot * 16) ^ ((d1 & 7) << 4)));
      }

    // ---- t = r + mask*log2e; row max via 4 chains ----
    float m4[4] = {-1e30f, -1e30f, -1e30f, -1e30f};
#pragma unroll
    for (int st = 0; st < 2; ++st) {
      f32x16& s = st ? sc1 : sc0;
#pragma unroll
      for (int rg = 0; rg < 4; ++rg) {
        float4 m = mk[st * 4 + rg];
#pragma unroll
        for (int i = 0; i < 4; ++i) {
          float v = fmaf(((const float*)&m)[i], L2E, s[rg * 4 + i]);
          s[rg * 4 + i] = v;
          m4[i] = fmaxf(m4[i], v);
        }
      }
    }
    float mt = fmaxf(fmaxf(m4[0], m4[1]), fmaxf(m4[2], m4[3]));
    mt = fmaxf(mt, __shfl_xor(mt, 32, 64));

    // ---- rare rescale: keep exp2 arg <= 24 (acc already holds PV(t-1): consistent) ----
    if (!__all(mt - rho <= 24.0f)) {
      float mw = mt;
#pragma unroll
      for (int off = 1; off < 32; off <<= 1) mw = fmaxf(mw, __shfl_xor(mw, off, 64));
      float fct = exp2_fast(rho - mw);   // uniform
      lrun *= fct;
#pragma unroll
      for (int i = 0; i < 16; ++i) { acc0[i] *= fct; acc1[i] *= fct; }
      rho = mw;
    }
    float rho_u = __builtin_amdgcn_readfirstlane(rho);
    if (rho_u != 0.0f) {
#pragma unroll
      for (int i = 0; i < 16; ++i) { sc0[i] -= rho_u; sc1[i] -= rho_u; }
    }

    // ---- p = exp2(t); sum via 4 chains ----
    float s4[4] = {0.f, 0.f, 0.f, 0.f};
#pragma unroll
    for (int st = 0; st < 2; ++st) {
      f32x16& s = st ? sc1 : sc0;
#pragma unroll
      for (int i = 0; i < 16; ++i) {
        float p = exp2_fast(s[i]);
        s[i] = p;
        s4[i & 3] += p;
      }
    }
    float ls = (s4[0] + s4[1]) + (s4[2] + s4[3]);
    ls += __shfl_xor(ls, 32, 64);
    lrun += ls;

    // ---- pack P(t) -> pbP (consumed next iteration) ----
#pragma unroll
    for (int st = 0; st < 2; ++st) {
      f32x16& s = st ? sc1 : sc0;
      unsigned a0 = pk2(s[0], s[1]),   b0 = pk2(s[4], s[5]);
      unsigned a1 = pk2(s[2], s[3]),   b1 = pk2(s[6], s[7]);
      unsigned a2 = pk2(s[8], s[9]),   b2 = pk2(s[12], s[13]);
      unsigned a3 = pk2(s[10], s[11]), b3 = pk2(s[14], s[15]);
      asm("v_permlane32_swap_b32 %0, %1" : "+v"(a0), "+v"(b0));
      asm("v_permlane32_swap_b32 %0, %1" : "+v"(a1), "+v"(b1));
      asm("v_permlane32_swap_b32 %0, %1" : "+v"(a2), "+v"(b2));
      asm("v_permlane32_swap_b32 %0, %1" : "+v"(a3), "+v"(b3));
      pbP[st * 2 + 0] = mk_frag(a0, a1, b0, b1);   // keys st*32 + 0..15
      pbP[st * 2 + 1] = mk_frag(a2, a3, b2, b3);   // keys st*32 + 16..31
    }

    // ---- write next V tile ----
    if (t < 31) {
      const u16* p0 = (const u16*)&v0; const u16* p1 = (const u16*)&v1;
      char* vb_n = (char*)Vb_[cur ^ 1];
#pragma unroll
      for (int j = 0; j < 4; ++j) {
        int d = dq * 4 + j;
        int w = (int)((unsigned)p0[j] | ((unsigned)p1[j] << 16));
        *(int*)(vb_n + d * 128 + ((4 * ka2) ^ ((d & 7) << 4))) = w;
      }
    }
    __syncthreads();
  }

  // ---- epilogue: flush PV(31) ----
  __builtin_amdgcn_s_setprio(1);
#pragma unroll
  for (int st = 0; st < 2; ++st)
#pragma unroll
    for (int ks2 = 0; ks2 < 2; ++ks2) {
      int i = st * 2 + ks2;
      acc0 = MFMA32x32x16(vaP[i * 2 + 0], pbP[i], acc0);
      acc1 = MFMA32x32x16(vaP[i * 2 + 1], pbP[i], acc1);
    }
  __builtin_amdgcn_s_setprio(0);

  // ---- D2 col=q=l31, row d = dh*32 + (r&3)+8*(r>>2)+4*hi ----
  float inv = 1.0f / lrun;
  bf16_t* cb = ctx + qrow * Hs + h * 64;
#pragma unroll
  for (int dh = 0; dh < 2; ++dh) {
    f32x16& a = dh ? acc1 : acc0;
#pragma unroll
    for (int rg = 0; rg < 4; ++rg) {
      ushort4 o;
      o.x = bits_of((bf16_t)(a[rg * 4 + 0] * inv));
      o.y = bits_of((bf16_t)(a[rg * 4 + 1] * inv));
      o.z = bits_of((bf16_t)(a[rg * 4 + 2] * inv));
      o.w = bits_of((bf16_t)(a[rg * 4 + 3] * inv));
      *(ushort4*)(cb + dh * 32 + rg * 8 + hi * 4) = o;
    }
  }
}

// ---------------- launcher ----------------
extern "C" void kernel_launch(void* const* d_in, const int* in_sizes, int n_in,
                              void* d_out, int out_size, void* d_ws, size_t ws_size,
                              hipStream_t stream) {
  (void)in_sizes; (void)n_in; (void)out_size; (void)ws_size;
  const float* X  = (const float*)d_in[0];
  const float* mask = (const float*)d_in[1];
  const float* Wq = (const float*)d_in[2];
  const float* bq = (const float*)d_in[3];
  const float* Wk = (const float*)d_in[4];
  const float* bk = (const float*)d_in[5];
  const float* Wv = (const float*)d_in[6];
  const float* bv = (const float*)d_in[7];
  const float* Wo = (const float*)d_in[8];
  const float* bo = (const float*)d_in[9];

  char* ws = (char*)d_ws;
  bf16_t* Xb  = (bf16_t*)(ws + 0);          // dead after QKV GEMM
  bf16_t* Wqb = (bf16_t*)(ws + 8388608);
  bf16_t* Wkb = (bf16_t*)(ws + 10485760);
  bf16_t* Wvb = (bf16_t*)(ws + 12582912);
  bf16_t* Wob = (bf16_t*)(ws + 14680064);   // LIVE until O-GEMM
  bf16_t* Qb  = (bf16_t*)(ws + 16777216);
  bf16_t* Kb  = (bf16_t*)(ws + 25165824);
  bf16_t* Vb  = (bf16_t*)(ws + 33554432);
  bf16_t* Cb  = (bf16_t*)(ws + 41943040);   // ctx bf16 (dedicated)

  cvt_all<<<8192, 256, 0, stream>>>((const float4*)X, (const float4*)Wq, (const float4*)Wk,
                                    (const float4*)Wv, (const float4*)Wo, (ushort4*)Xb);

  // QKV projections; Q pre-scaled by 0.125*log2e so attention scores are log2-domain
  const float QSCALE = 0.125f * 1.4426950408889634f;
  dim3 gq(32, 8, 3);
  gemm_bt<<<gq, 256, 0, stream>>>(Xb, Wqb, Wkb, Wvb, bq, bk, bv, Qb, Kb, Vb,
                                  QSCALE, 1.0f, 1.0f);

  // attention (QBLK=256, 8-wave staging amortization)
  dim3 ga(8, 32, 1);
  attn_fwd11<<<ga, 512, 0, stream>>>(Qb, Kb, Vb, mask, Cb);

  // output projection -> f32 d_out (128x64 tiles, 512 blocks = 2/CU)
  dim3 go(32, 16, 1);
  gemm_o64<<<go, 256, 0, stream>>>(Cb, Wob, bo, (float*)d_out);
}